// Round 12
// baseline (2275.179 us; speedup 1.0000x reference)
//
#include <hip/hip_runtime.h>
#include <stdint.h>

#define Nn 65536
#define Ee 131072
#define Dd 512
#define D2 1024
#define Ll 5
#define Gg 512
#define EPSf 1e-5f

typedef _Float16 f16x8 __attribute__((ext_vector_type(8)));
typedef float f32x4 __attribute__((ext_vector_type(4)));
typedef unsigned short u16x8 __attribute__((ext_vector_type(8)));

__device__ __forceinline__ unsigned short f2h(float f) {
    _Float16 h = (_Float16)f;  // v_cvt_f16_f32, RNE
    union { _Float16 h; unsigned short u; } c; c.h = h;
    return c.u;
}

__device__ __forceinline__ float h2f(unsigned short s) {
    union { unsigned short s; _Float16 h; } c; c.s = s;
    return (float)c.h;
}

__device__ __forceinline__ void gload_lds16(const void* g, void* l) {
    __builtin_amdgcn_global_load_lds(
        (const __attribute__((address_space(1))) void*)(uintptr_t)g,
        (__attribute__((address_space(3))) void*)(unsigned)(uintptr_t)l,
        16, 0, 0);
}

// ---------------- weight transpose: src [L][K][Nw] f32 -> dst [L][Nw][K] f16
__global__ void k_transW(const float* __restrict__ src, unsigned short* __restrict__ dst,
                         int K, int Nw) {
    long total = (long)Ll * K * Nw;
    for (long idx = (long)blockIdx.x * blockDim.x + threadIdx.x; idx < total;
         idx += (long)gridDim.x * blockDim.x) {
        long l = idx / ((long)K * Nw);
        long rem = idx - l * (long)K * Nw;
        int k = (int)(rem / Nw), n = (int)(rem % Nw);
        dst[(l * Nw + n) * K + k] = f2h(src[idx]);
    }
}

// ---------------- edge-embedding table: E[l][18][512] = ee1[l][j/3] + ee2[l][j%3]
__global__ void k_etab(const float* __restrict__ ee1, const float* __restrict__ ee2,
                       float* __restrict__ E) {
    int idx = blockIdx.x * blockDim.x + threadIdx.x;
    const int total = Ll * 18 * Dd;
    if (idx < total) {
        int l = idx / (18 * Dd);
        int rem = idx - l * 18 * Dd;
        int j = rem / Dd, c = rem - j * Dd;
        int a0 = j / 3, a1 = j - a0 * 3;
        E[idx] = ee1[((size_t)l * 6 + a0) * Dd + c] + ee2[((size_t)l * 3 + a1) * Dd + c];
    }
}

// ---------------- atom embedding -> f16 h0 (into hhf)
__global__ void k_embed(const int* __restrict__ x,
                        const float* __restrict__ xe1, const float* __restrict__ xe2,
                        unsigned short* __restrict__ hhf) {
    const int total = Nn * 64;
    for (int idx = blockIdx.x * blockDim.x + threadIdx.x; idx < total;
         idx += gridDim.x * blockDim.x) {
        int node = idx >> 6, c8 = (idx & 63) * 8;
        int t0 = x[2 * node], t1 = x[2 * node + 1];
        const float4* p1 = (const float4*)(xe1 + (size_t)t0 * Dd + c8);
        const float4* p2 = (const float4*)(xe2 + (size_t)t1 * Dd + c8);
        float4 a0 = p1[0], a1 = p1[1], b0 = p2[0], b1 = p2[1];
        u16x8 o;
        o[0] = f2h(a0.x + b0.x); o[1] = f2h(a0.y + b0.y);
        o[2] = f2h(a0.z + b0.z); o[3] = f2h(a0.w + b0.w);
        o[4] = f2h(a1.x + b1.x); o[5] = f2h(a1.y + b1.y);
        o[6] = f2h(a1.z + b1.z); o[7] = f2h(a1.w + b1.w);
        *(u16x8*)(hhf + (size_t)node * Dd + c8) = o;
    }
}

// ---------------- CSR build (dst-sorted), deterministic after k_sort
__global__ void k_zeroN(int* __restrict__ p, int n) {
    int i = blockIdx.x * blockDim.x + threadIdx.x;
    if (i < n) p[i] = 0;
}

__global__ void k_hist(const int* __restrict__ edst, int* __restrict__ cnt) {
    int e = blockIdx.x * blockDim.x + threadIdx.x;
    if (e < Ee) atomicAdd(&cnt[edst[e]], 1);
}

__global__ void k_scan(const int* __restrict__ cnt, int* __restrict__ off,
                       int* __restrict__ cursor) {
    __shared__ int part[1024];
    int t = threadIdx.x;
    int base = t * 64;
    int s = 0;
    for (int i = 0; i < 64; ++i) s += cnt[base + i];
    part[t] = s;
    __syncthreads();
    for (int d = 1; d < 1024; d <<= 1) {
        int v = (t >= d) ? part[t - d] : 0;
        __syncthreads();
        part[t] += v;
        __syncthreads();
    }
    int run = part[t] - s;  // exclusive prefix
    for (int i = 0; i < 64; ++i) {
        off[base + i] = run;
        cursor[base + i] = run;
        run += cnt[base + i];
    }
    if (t == 1023) off[Nn] = run;
}

// key = edge_idx*32 + attr (attr = a0*3+a1 in 0..8); unique keys
__global__ void k_place(const int* __restrict__ esrc, const int* __restrict__ edst,
                        const int* __restrict__ eattr, int* __restrict__ cursor,
                        int* __restrict__ ckey, int* __restrict__ csrc) {
    int e = blockIdx.x * blockDim.x + threadIdx.x;
    if (e < Ee) {
        int d = edst[e];
        int p = atomicAdd(&cursor[d], 1);
        ckey[p] = e * 32 + (eattr[2 * e] * 3 + eattr[2 * e + 1]);
        csrc[p] = esrc[e];
    }
}

// per-node insertion sort by key -> CSR bit-identical on every call
__global__ void k_sort(const int* __restrict__ off, int* __restrict__ ckey,
                       int* __restrict__ csrc) {
    int node = blockIdx.x * blockDim.x + threadIdx.x;
    if (node >= Nn) return;
    int kb = off[node], ke = off[node + 1];
    for (int i = kb + 1; i < ke; ++i) {
        int k = ckey[i], s = csrc[i];
        int j = i - 1;
        while (j >= kb && ckey[j] > k) {
            ckey[j + 1] = ckey[j]; csrc[j + 1] = csrc[j]; --j;
        }
        ckey[j + 1] = k; csrc[j + 1] = s;
    }
}

// ---------------- gather: agg[n] = act(h[n]) + E[12] + sum_e (act(h[src]) + E[attr]) -> f16
template <int NORM>
__global__ __launch_bounds__(256) void k_gather(const unsigned short* __restrict__ hf16,
                                                const float* __restrict__ ss,
                                                const int* __restrict__ off,
                                                const int* __restrict__ ckey,
                                                const int* __restrict__ csrc,
                                                const float* __restrict__ El,
                                                unsigned short* __restrict__ aggh) {
    int node = (blockIdx.x << 2) + (threadIdx.x >> 6);
    int lane = threadIdx.x & 63;
    int c8 = lane * 8;
    float sa[8], sb[8];
    if (NORM) {
        float4 a0 = *(const float4*)(ss + c8), a1 = *(const float4*)(ss + c8 + 4);
        float4 b0 = *(const float4*)(ss + 512 + c8), b1 = *(const float4*)(ss + 512 + c8 + 4);
        sa[0] = a0.x; sa[1] = a0.y; sa[2] = a0.z; sa[3] = a0.w;
        sa[4] = a1.x; sa[5] = a1.y; sa[6] = a1.z; sa[7] = a1.w;
        sb[0] = b0.x; sb[1] = b0.y; sb[2] = b0.z; sb[3] = b0.w;
        sb[4] = b1.x; sb[5] = b1.y; sb[6] = b1.z; sb[7] = b1.w;
    }
    float acc[8];
    {
        u16x8 v = *(const u16x8*)(hf16 + (size_t)node * Dd + c8);
        float4 e0 = *(const float4*)(El + 12 * Dd + c8);
        float4 e1 = *(const float4*)(El + 12 * Dd + c8 + 4);
        float ev[8];
        ev[0] = e0.x; ev[1] = e0.y; ev[2] = e0.z; ev[3] = e0.w;
        ev[4] = e1.x; ev[5] = e1.y; ev[6] = e1.z; ev[7] = e1.w;
#pragma unroll
        for (int i = 0; i < 8; ++i) {
            float hv = h2f(v[i]);
            if (NORM) hv = fmaxf(fmaf(hv, sa[i], sb[i]), 0.f);
            acc[i] = hv + ev[i];
        }
    }
    int kb = off[node], ke = off[node + 1];
    for (int k = kb; k < ke; ++k) {
        int src = csrc[k];
        int at = ckey[k] & 31;
        u16x8 v = *(const u16x8*)(hf16 + (size_t)src * Dd + c8);
        const float* Er = El + (size_t)at * Dd + c8;
        float4 e0 = *(const float4*)(Er);
        float4 e1 = *(const float4*)(Er + 4);
        float ev[8];
        ev[0] = e0.x; ev[1] = e0.y; ev[2] = e0.z; ev[3] = e0.w;
        ev[4] = e1.x; ev[5] = e1.y; ev[6] = e1.z; ev[7] = e1.w;
#pragma unroll
        for (int i = 0; i < 8; ++i) {
            float hv = h2f(v[i]);
            if (NORM) hv = fmaxf(fmaf(hv, sa[i], sb[i]), 0.f);
            acc[i] += hv + ev[i];
        }
    }
    u16x8 o;
#pragma unroll
    for (int i = 0; i < 8; ++i) o[i] = f2h(acc[i]);
    *(u16x8*)(aggh + (size_t)node * Dd + c8) = o;
}

// ================ GEMM "B-direct": 256x256 tile, 8 waves as 4M x 2N, BK=64.
// A staged in LDS (4 parities x 32KB, 3 tiles ahead, vmcnt(8)+barrier once/tile).
// B (weights, L2-resident) loaded per-lane direct from global -> L1 broadcast.
// LDS read insts halved vs 2Mx4N (A re-read 2x not 4x); B dup goes to L1.
__device__ __forceinline__ void stage_q(const unsigned short* __restrict__ g, int ldk,
                                        long row0, int col0, char* region, int tid) {
    int wbase = (tid >> 6) << 10;  // wave * 1024 bytes
#pragma unroll
    for (int r = 0; r < 2; ++r) {
        int gi = tid + r * 512;            // granule 0..1023
        int row = gi >> 2;
        int k16 = (gi & 3) ^ ((row >> 1) & 3);
        gload_lds16(g + (row0 + row) * (long)ldk + col0 + k16 * 8,
                    region + r * 8192 + wbase);
    }
}

__device__ __forceinline__ f16x8 rd_frag(const char* region, int row, int l4) {
    int slot = l4 ^ ((row >> 1) & 3);
    return *(const f16x8*)(region + row * 64 + (slot << 4));
}

template <int EPI, int KK>
__global__ __launch_bounds__(512, 2) void gemm_bd(const unsigned short* __restrict__ A,
                                                  const unsigned short* __restrict__ BT,
                                                  const float* __restrict__ bias,
                                                  unsigned short* __restrict__ Cb,
                                                  float* __restrict__ pS,
                                                  int M, int N) {
    __shared__ __align__(16) char lds[131072];   // 4 parities x 32KB (A only)
    const int tid = threadIdx.x;
    const int lane = tid & 63;
    const int w = tid >> 6;
    const int wm = w >> 1, wn = w & 1;           // 4M x 2N
    const int l15 = lane & 15, l4 = lane >> 4;

    // XCD-aware swizzle (nwg % 8 == 0 for our shapes)
    const int nwg = gridDim.x;
    const int cpx = nwg >> 3;
    const int bid = blockIdx.x;
    const int wg = (bid & 7) * cpx + (bid >> 3);
    const int ntn = N >> 8;
    const long bm = (long)(wg / ntn) * 256;
    const long bn = (long)(wg % ntn) * 256;

    const int NT = KK >> 6;   // BK=64

    // per-lane B pointer: row = bn + wn*128 + l15 (+fn*16 via offset), k = l4*8
    const unsigned short* Bl = BT + (size_t)(bn + wn * 128 + l15) * KK + l4 * 8;

    f32x4 acc[4][8];
#pragma unroll
    for (int i = 0; i < 4; ++i)
#pragma unroll
        for (int j = 0; j < 8; ++j) acc[i][j] = (f32x4){0.f, 0.f, 0.f, 0.f};

    // ---- prologue: stage tiles 0,1,2 into parities 0,1,2; retire tile 0
    stage_q(A, KK, bm, 0, lds, tid);
    stage_q(A, KK, bm, 32, lds + 16384, tid);
    stage_q(A, KK, bm, 64, lds + 32768, tid);
    stage_q(A, KK, bm, 96, lds + 32768 + 16384, tid);
    stage_q(A, KK, bm, 128, lds + 65536, tid);
    stage_q(A, KK, bm, 160, lds + 65536 + 16384, tid);
    asm volatile("s_waitcnt vmcnt(8)" ::: "memory");
    __builtin_amdgcn_s_barrier();
    asm volatile("" ::: "memory");

    for (int t = 0; t < NT; ++t) {
        const char* Ac = lds + (size_t)(t & 3) * 32768;
        const unsigned short* Bt = Bl + t * 64;
        f16x8 af0[4], af1[4], bv0[8], bv1[8];
        // ALL global bv loads issued BEFORE the stage, so the compiler's
        // bv-wait (vmcnt) never forces the async stages to drain.
#pragma unroll
        for (int fn = 0; fn < 8; ++fn)
            bv0[fn] = *(const f16x8*)(Bt + (size_t)fn * 16 * KK);
#pragma unroll
        for (int fn = 0; fn < 8; ++fn)
            bv1[fn] = *(const f16x8*)(Bt + (size_t)fn * 16 * KK + 32);
        // A fragments (lgkmcnt path, independent of vmcnt)
#pragma unroll
        for (int fm = 0; fm < 4; ++fm)
            af0[fm] = rd_frag(Ac, wm * 64 + fm * 16 + l15, l4);
#pragma unroll
        for (int fm = 0; fm < 4; ++fm)
            af1[fm] = rd_frag(Ac + 16384, wm * 64 + fm * 16 + l15, l4);
        if (t + 3 < NT) {
            char* dst = lds + (size_t)((t + 3) & 3) * 32768;
            stage_q(A, KK, bm, (t + 3) * 64, dst, tid);
            stage_q(A, KK, bm, (t + 3) * 64 + 32, dst + 16384, tid);
        }
#pragma unroll
        for (int fm = 0; fm < 4; ++fm)
#pragma unroll
            for (int fn = 0; fn < 8; ++fn)
                acc[fm][fn] = __builtin_amdgcn_mfma_f32_16x16x32_f16(af0[fm], bv0[fn], acc[fm][fn], 0, 0, 0);
#pragma unroll
        for (int fm = 0; fm < 4; ++fm)
#pragma unroll
            for (int fn = 0; fn < 8; ++fn)
                acc[fm][fn] = __builtin_amdgcn_mfma_f32_16x16x32_f16(af1[fm], bv1[fn], acc[fm][fn], 0, 0, 0);
        if (t + 3 < NT) {
            asm volatile("s_waitcnt vmcnt(8)" ::: "memory");   // retire tile t+1
        } else if (t + 2 < NT) {
            asm volatile("s_waitcnt vmcnt(4)" ::: "memory");
        } else if (t + 1 < NT) {
            asm volatile("s_waitcnt vmcnt(0)" ::: "memory");
        }
        __builtin_amdgcn_s_barrier();
        asm volatile("" ::: "memory");
    }

    // ---- epilogue: LDS-staged coalesced f16 C write (+stats for EPI 1)
    unsigned short* cl = (unsigned short*)lds;
    float cs[8], cq[8];
#pragma unroll
    for (int i = 0; i < 8; ++i) { cs[i] = 0.f; cq[i] = 0.f; }
#pragma unroll
    for (int q = 0; q < 4; ++q) {
        __syncthreads();
        if (wm == q) {
#pragma unroll
            for (int fn = 0; fn < 8; ++fn) {
                int col = wn * 128 + fn * 16 + l15;
                float bval = bias[bn + col];
#pragma unroll
                for (int fm = 0; fm < 4; ++fm) {
                    int r0 = fm * 16 + l4 * 4;
#pragma unroll
                    for (int r = 0; r < 4; ++r) {
                        float v = acc[fm][fn][r] + bval;
                        if (EPI == 0) v = fmaxf(v, 0.f);
                        else { cs[fn] += v; cq[fn] += v * v; }
                        cl[(r0 + r) * 264 + col] = f2h(v);
                    }
                }
            }
        }
        __syncthreads();
#pragma unroll
        for (int i = 0; i < 4; ++i) {
            int g = tid + i * 512;
            int r = g >> 5, cg = (g & 31) << 3;
            u16x8 val = *(const u16x8*)&cl[r * 264 + cg];
            *(u16x8*)&Cb[(bm + q * 64 + r) * N + bn + cg] = val;
        }
    }
    if (EPI == 1) {
#pragma unroll
        for (int fn = 0; fn < 8; ++fn) {
            float s = cs[fn], q = cq[fn];
            s += __shfl_xor(s, 16); s += __shfl_xor(s, 32);
            q += __shfl_xor(q, 16); q += __shfl_xor(q, 32);
            if (l4 == 0) {
                int col = (int)bn + wn * 128 + fn * 16 + l15;
                int rowgrp = (int)(bm >> 6) + wm;   // [0,1024), 64-row groups
                pS[rowgrp * 512 + col] = s;
                pS[524288 + rowgrp * 512 + col] = q;
            }
        }
    }
}

// ---------------- BN reduce, 2-stage parallel (fixed order -> deterministic)
__global__ void k_bnA(const float* __restrict__ pS, float* __restrict__ pT) {
    int b = blockIdx.x;   // 64 blocks, 16 rowgrps each
    int t = threadIdx.x;  // 256
    float s0 = 0.f, s1 = 0.f, q0 = 0.f, q1 = 0.f;
#pragma unroll
    for (int i = 0; i < 16; ++i) {
        int rg = b * 16 + i;
        s0 += pS[rg * 512 + t];
        s1 += pS[rg * 512 + t + 256];
        q0 += pS[524288 + rg * 512 + t];
        q1 += pS[524288 + rg * 512 + t + 256];
    }
    pT[b * 512 + t] = s0;
    pT[b * 512 + t + 256] = s1;
    pT[32768 + b * 512 + t] = q0;
    pT[32768 + b * 512 + t + 256] = q1;
}

__global__ void k_bnB(const float* __restrict__ pT, const float* __restrict__ gamma,
                      const float* __restrict__ beta, float* __restrict__ ss) {
    int c = threadIdx.x;  // 512
    float s = 0.f, q = 0.f;
    for (int b = 0; b < 64; ++b) {
        s += pT[b * 512 + c];
        q += pT[32768 + b * 512 + c];
    }
    float mean = s * (1.f / (float)Nn);
    float var = q * (1.f / (float)Nn) - mean * mean;
    float a = gamma[c] * rsqrtf(var + EPSf);
    ss[c] = a;
    ss[512 + c] = beta[c] - mean * a;
}

// ---------------- final BN normalize (no relu): f16 hh -> f32 h (d_out)
__global__ void k_norm(const unsigned short* __restrict__ hhf, const float* __restrict__ ss,
                       float4* __restrict__ h4) {
    const int total = Nn * 128;
    const float4* ss4 = (const float4*)ss;
    for (int idx = blockIdx.x * blockDim.x + threadIdx.x; idx < total;
         idx += gridDim.x * blockDim.x) {
        int c = idx & 127;
        ushort4 u = *(const ushort4*)(hhf + (size_t)idx * 4);
        float4 v = make_float4(h2f(u.x), h2f(u.y), h2f(u.z), h2f(u.w));
        float4 a = ss4[c], b = ss4[128 + c];
        v.x = fmaf(v.x, a.x, b.x); v.y = fmaf(v.y, a.y, b.y);
        v.z = fmaf(v.z, a.z, b.z); v.w = fmaf(v.w, a.w, b.w);
        h4[idx] = v;
    }
}

// ---------------- graph mean pool: read f16 hh + fused BN affine (batch sorted)
__global__ void k_pool(const unsigned short* __restrict__ hhf, const float* __restrict__ ss,
                       const int* __restrict__ batch, float* __restrict__ graph) {
    int g = blockIdx.x, t = threadIdx.x;  // 512 blocks, 256 threads
    int lo = 0, hi = Nn;
    while (lo < hi) { int m = (lo + hi) >> 1; if (batch[m] < g) lo = m + 1; else hi = m; }
    int s = lo;
    lo = s; hi = Nn;
    while (lo < hi) { int m = (lo + hi) >> 1; if (batch[m] <= g) lo = m + 1; else hi = m; }
    int e = lo;
    float a0 = ss[t], a1 = ss[t + 256];
    float b0 = ss[512 + t], b1 = ss[512 + t + 256];
    float s0 = 0.f, s1 = 0.f;
    for (int r = s; r < e; ++r) {
        const unsigned short* row = hhf + (size_t)r * Dd;
        s0 += fmaf(h2f(row[t]), a0, b0);
        s1 += fmaf(h2f(row[t + 256]), a1, b1);
    }
    int cnt = e - s; if (cnt < 1) cnt = 1;
    float inv = 1.f / (float)cnt;
    graph[(long)g * Dd + t] = s0 * inv;
    graph[(long)g * Dd + t + 256] = s1 * inv;
}

extern "C" void kernel_launch(void* const* d_in, const int* in_sizes, int n_in,
                              void* d_out, int out_size, void* d_ws, size_t ws_size,
                              hipStream_t stream) {
    (void)in_sizes; (void)n_in; (void)out_size; (void)ws_size;
    const int* x      = (const int*)d_in[0];
    const int* ei     = (const int*)d_in[1];
    const int* ea     = (const int*)d_in[2];
    const int* batch  = (const int*)d_in[3];
    const float* xe1  = (const float*)d_in[4];
    const float* xe2  = (const float*)d_in[5];
    const float* ee1  = (const float*)d_in[6];
    const float* ee2  = (const float*)d_in[7];
    const float* W1   = (const float*)d_in[8];
    const float* b1   = (const float*)d_in[9];
    const float* W2   = (const float*)d_in[10];
    const float* b2   = (const float*)d_in[11];
    const float* gamma = (const float*)d_in[12];
    const float* beta  = (const float*)d_in[13];

    float* graph = (float*)d_out;
    float* h = graph + (size_t)Gg * Dd;  // N*D f32; aliased as hh1 f16 [N][2D]

    // d_ws layout (~145 MB): small/index arrays FIRST, then big buffers.
    char* w = (char*)d_ws;
    int* csr_off = (int*)w;                     w += (Nn + 1) * 4;
    int* cursor = (int*)w;                      w += Nn * 4;
    int* cnt = (int*)w;                         w += Nn * 4;
    int* ckey = (int*)w;                        w += Ee * 4;
    int* csrc = (int*)w;                        w += Ee * 4;
    float* ss = (float*)w;                      w += 4096;
    float* pS = (float*)w;                      w += 2 * 1024 * 512 * 4;    // BN partials, 4 MB
    float* pT = (float*)w;                      w += 2 * 64 * 512 * 4;      // BN stage-2, 256 KB
    float* Etab = (float*)w;                    w += (size_t)Ll * 18 * Dd * 4;  // 184 KB
    unsigned short* aggh = (unsigned short*)w;  w += (size_t)Nn * Dd * 2;   // agg f16, 64 MB
    unsigned short* hhf = (unsigned short*)w;   w += (size_t)Nn * Dd * 2;   // hh f16, 64 MB
    unsigned short* w1t = (unsigned short*)w;   w += (size_t)Ll * D2 * Dd * 2;
    unsigned short* w2t = (unsigned short*)w;   w += (size_t)Ll * Dd * D2 * 2;

    // weights -> f16 transposed [N][K]; edge-emb table; atom embedding (f16 h0)
    k_transW<<<2048, 256, 0, stream>>>(W1, w1t, Dd, D2);
    k_transW<<<2048, 256, 0, stream>>>(W2, w2t, D2, Dd);
    k_etab<<<(Ll * 18 * Dd + 255) / 256, 256, 0, stream>>>(ee1, ee2, Etab);
    k_embed<<<2048, 256, 0, stream>>>(x, xe1, xe2, hhf);

    // CSR build (topology constant across layers); sorted -> bit-deterministic
    k_zeroN<<<64, 1024, 0, stream>>>(cnt, Nn);
    k_hist<<<Ee / 256, 256, 0, stream>>>(ei + Ee, cnt);
    k_scan<<<1, 1024, 0, stream>>>(cnt, csr_off, cursor);
    k_place<<<Ee / 256, 256, 0, stream>>>(ei, ei + Ee, ea, cursor, ckey, csrc);
    k_sort<<<Nn / 256, 256, 0, stream>>>(csr_off, ckey, csrc);

    for (int l = 0; l < Ll; ++l) {
        const float* El = Etab + (size_t)l * 18 * Dd;
        if (l == 0)
            k_gather<0><<<Nn / 4, 256, 0, stream>>>(hhf, nullptr, csr_off, ckey, csrc,
                                                    El, aggh);
        else
            k_gather<1><<<Nn / 4, 256, 0, stream>>>(hhf, ss, csr_off, ckey, csrc,
                                                    El, aggh);
        gemm_bd<0, Dd><<<(Nn / 256) * (D2 / 256), 512, 0, stream>>>(
            aggh, w1t + (size_t)l * D2 * Dd, b1 + (size_t)l * D2,
            (unsigned short*)h, nullptr, Nn, D2);
        gemm_bd<1, D2><<<(Nn / 256) * (Dd / 256), 512, 0, stream>>>(
            (const unsigned short*)h, w2t + (size_t)l * Dd * D2, b2 + (size_t)l * Dd,
            hhf, pS, Nn, Dd);
        k_bnA<<<64, 256, 0, stream>>>(pS, pT);
        k_bnB<<<1, 512, 0, stream>>>(pT, gamma + (size_t)l * Dd, beta + (size_t)l * Dd, ss);
    }

    // final-layer BN (no relu) -> h f32, then pool (pool reads f16 hh directly)
    k_norm<<<2048, 256, 0, stream>>>(hhf, ss, (float4*)h);
    k_pool<<<Gg, 256, 0, stream>>>(hhf, ss, batch, graph);
}

// Round 13
// 1566.853 us; speedup vs baseline: 1.4521x; 1.4521x over previous
//
#include <hip/hip_runtime.h>
#include <stdint.h>

#define Nn 65536
#define Ee 131072
#define Dd 512
#define D2 1024
#define Ll 5
#define Gg 512
#define EPSf 1e-5f

typedef _Float16 f16x8 __attribute__((ext_vector_type(8)));
typedef float f32x4 __attribute__((ext_vector_type(4)));
typedef unsigned short u16x8 __attribute__((ext_vector_type(8)));

__device__ __forceinline__ unsigned short f2h(float f) {
    _Float16 h = (_Float16)f;  // v_cvt_f16_f32, RNE
    union { _Float16 h; unsigned short u; } c; c.h = h;
    return c.u;
}

__device__ __forceinline__ float h2f(unsigned short s) {
    union { unsigned short s; _Float16 h; } c; c.s = s;
    return (float)c.h;
}

__device__ __forceinline__ void gload_lds16(const void* g, void* l) {
    __builtin_amdgcn_global_load_lds(
        (const __attribute__((address_space(1))) void*)(uintptr_t)g,
        (__attribute__((address_space(3))) void*)(unsigned)(uintptr_t)l,
        16, 0, 0);
}

// ---------------- weight transpose: src [L][K][Nw] f32 -> dst [L][Nw][K] f16
__global__ void k_transW(const float* __restrict__ src, unsigned short* __restrict__ dst,
                         int K, int Nw) {
    long total = (long)Ll * K * Nw;
    for (long idx = (long)blockIdx.x * blockDim.x + threadIdx.x; idx < total;
         idx += (long)gridDim.x * blockDim.x) {
        long l = idx / ((long)K * Nw);
        long rem = idx - l * (long)K * Nw;
        int k = (int)(rem / Nw), n = (int)(rem % Nw);
        dst[(l * Nw + n) * K + k] = f2h(src[idx]);
    }
}

// ---------------- edge-embedding table: E[l][18][512] = ee1[l][j/3] + ee2[l][j%3]
__global__ void k_etab(const float* __restrict__ ee1, const float* __restrict__ ee2,
                       float* __restrict__ E) {
    int idx = blockIdx.x * blockDim.x + threadIdx.x;
    const int total = Ll * 18 * Dd;
    if (idx < total) {
        int l = idx / (18 * Dd);
        int rem = idx - l * 18 * Dd;
        int j = rem / Dd, c = rem - j * Dd;
        int a0 = j / 3, a1 = j - a0 * 3;
        E[idx] = ee1[((size_t)l * 6 + a0) * Dd + c] + ee2[((size_t)l * 3 + a1) * Dd + c];
    }
}

// ---------------- atom embedding -> f16 h0 (into hhf)
__global__ void k_embed(const int* __restrict__ x,
                        const float* __restrict__ xe1, const float* __restrict__ xe2,
                        unsigned short* __restrict__ hhf) {
    const int total = Nn * 64;
    for (int idx = blockIdx.x * blockDim.x + threadIdx.x; idx < total;
         idx += gridDim.x * blockDim.x) {
        int node = idx >> 6, c8 = (idx & 63) * 8;
        int t0 = x[2 * node], t1 = x[2 * node + 1];
        const float4* p1 = (const float4*)(xe1 + (size_t)t0 * Dd + c8);
        const float4* p2 = (const float4*)(xe2 + (size_t)t1 * Dd + c8);
        float4 a0 = p1[0], a1 = p1[1], b0 = p2[0], b1 = p2[1];
        u16x8 o;
        o[0] = f2h(a0.x + b0.x); o[1] = f2h(a0.y + b0.y);
        o[2] = f2h(a0.z + b0.z); o[3] = f2h(a0.w + b0.w);
        o[4] = f2h(a1.x + b1.x); o[5] = f2h(a1.y + b1.y);
        o[6] = f2h(a1.z + b1.z); o[7] = f2h(a1.w + b1.w);
        *(u16x8*)(hhf + (size_t)node * Dd + c8) = o;
    }
}

// ---------------- CSR build (dst-sorted), deterministic after k_sort
__global__ void k_zeroN(int* __restrict__ p, int n) {
    int i = blockIdx.x * blockDim.x + threadIdx.x;
    if (i < n) p[i] = 0;
}

__global__ void k_hist(const int* __restrict__ edst, int* __restrict__ cnt) {
    int e = blockIdx.x * blockDim.x + threadIdx.x;
    if (e < Ee) atomicAdd(&cnt[edst[e]], 1);
}

__global__ void k_scan(const int* __restrict__ cnt, int* __restrict__ off,
                       int* __restrict__ cursor) {
    __shared__ int part[1024];
    int t = threadIdx.x;
    int base = t * 64;
    int s = 0;
    for (int i = 0; i < 64; ++i) s += cnt[base + i];
    part[t] = s;
    __syncthreads();
    for (int d = 1; d < 1024; d <<= 1) {
        int v = (t >= d) ? part[t - d] : 0;
        __syncthreads();
        part[t] += v;
        __syncthreads();
    }
    int run = part[t] - s;  // exclusive prefix
    for (int i = 0; i < 64; ++i) {
        off[base + i] = run;
        cursor[base + i] = run;
        run += cnt[base + i];
    }
    if (t == 1023) off[Nn] = run;
}

// key = edge_idx*32 + attr (attr = a0*3+a1 in 0..8); unique keys
__global__ void k_place(const int* __restrict__ esrc, const int* __restrict__ edst,
                        const int* __restrict__ eattr, int* __restrict__ cursor,
                        int* __restrict__ ckey, int* __restrict__ csrc) {
    int e = blockIdx.x * blockDim.x + threadIdx.x;
    if (e < Ee) {
        int d = edst[e];
        int p = atomicAdd(&cursor[d], 1);
        ckey[p] = e * 32 + (eattr[2 * e] * 3 + eattr[2 * e + 1]);
        csrc[p] = esrc[e];
    }
}

// per-node insertion sort by key -> CSR bit-identical on every call
__global__ void k_sort(const int* __restrict__ off, int* __restrict__ ckey,
                       int* __restrict__ csrc) {
    int node = blockIdx.x * blockDim.x + threadIdx.x;
    if (node >= Nn) return;
    int kb = off[node], ke = off[node + 1];
    for (int i = kb + 1; i < ke; ++i) {
        int k = ckey[i], s = csrc[i];
        int j = i - 1;
        while (j >= kb && ckey[j] > k) {
            ckey[j + 1] = ckey[j]; csrc[j + 1] = csrc[j]; --j;
        }
        ckey[j + 1] = k; csrc[j + 1] = s;
    }
}

// ---------------- gather: agg[n] = act(h[n]) + E[12] + sum_e (act(h[src]) + E[attr]) -> f16
template <int NORM>
__global__ __launch_bounds__(256) void k_gather(const unsigned short* __restrict__ hf16,
                                                const float* __restrict__ ss,
                                                const int* __restrict__ off,
                                                const int* __restrict__ ckey,
                                                const int* __restrict__ csrc,
                                                const float* __restrict__ El,
                                                unsigned short* __restrict__ aggh) {
    int node = (blockIdx.x << 2) + (threadIdx.x >> 6);
    int lane = threadIdx.x & 63;
    int c8 = lane * 8;
    float sa[8], sb[8];
    if (NORM) {
        float4 a0 = *(const float4*)(ss + c8), a1 = *(const float4*)(ss + c8 + 4);
        float4 b0 = *(const float4*)(ss + 512 + c8), b1 = *(const float4*)(ss + 512 + c8 + 4);
        sa[0] = a0.x; sa[1] = a0.y; sa[2] = a0.z; sa[3] = a0.w;
        sa[4] = a1.x; sa[5] = a1.y; sa[6] = a1.z; sa[7] = a1.w;
        sb[0] = b0.x; sb[1] = b0.y; sb[2] = b0.z; sb[3] = b0.w;
        sb[4] = b1.x; sb[5] = b1.y; sb[6] = b1.z; sb[7] = b1.w;
    }
    float acc[8];
    {
        u16x8 v = *(const u16x8*)(hf16 + (size_t)node * Dd + c8);
        float4 e0 = *(const float4*)(El + 12 * Dd + c8);
        float4 e1 = *(const float4*)(El + 12 * Dd + c8 + 4);
        float ev[8];
        ev[0] = e0.x; ev[1] = e0.y; ev[2] = e0.z; ev[3] = e0.w;
        ev[4] = e1.x; ev[5] = e1.y; ev[6] = e1.z; ev[7] = e1.w;
#pragma unroll
        for (int i = 0; i < 8; ++i) {
            float hv = h2f(v[i]);
            if (NORM) hv = fmaxf(fmaf(hv, sa[i], sb[i]), 0.f);
            acc[i] = hv + ev[i];
        }
    }
    int kb = off[node], ke = off[node + 1];
    for (int k = kb; k < ke; ++k) {
        int src = csrc[k];
        int at = ckey[k] & 31;
        u16x8 v = *(const u16x8*)(hf16 + (size_t)src * Dd + c8);
        const float* Er = El + (size_t)at * Dd + c8;
        float4 e0 = *(const float4*)(Er);
        float4 e1 = *(const float4*)(Er + 4);
        float ev[8];
        ev[0] = e0.x; ev[1] = e0.y; ev[2] = e0.z; ev[3] = e0.w;
        ev[4] = e1.x; ev[5] = e1.y; ev[6] = e1.z; ev[7] = e1.w;
#pragma unroll
        for (int i = 0; i < 8; ++i) {
            float hv = h2f(v[i]);
            if (NORM) hv = fmaxf(fmaf(hv, sa[i], sb[i]), 0.f);
            acc[i] += hv + ev[i];
        }
    }
    u16x8 o;
#pragma unroll
    for (int i = 0; i < 8; ++i) o[i] = f2h(acc[i]);
    *(u16x8*)(aggh + (size_t)node * Dd + c8) = o;
}

// ================ big-wave-tile GEMM: 256x256 block, 4 waves (2M x 2N),
// wave tile 128x128 (acc[8][8] = 256 VGPR, 1 wave/SIMD), BK=32,
// 3-buffer LDS (96KB) staged 2 tiles ahead, vmcnt(8)+barrier per tile.
// LDS reads/K-tile: 4x(128+128)x32x2 = 64KB vs 96KB for the 8-wave 2Mx4N split.
__device__ __forceinline__ void stage_r(const unsigned short* __restrict__ g, int ldk,
                                        long row0, int col0, char* region, int tid) {
    int wbase = (tid >> 6) << 10;  // wave * 1024 bytes
#pragma unroll
    for (int r = 0; r < 4; ++r) {
        int gi = tid + r * 256;            // granule 0..1023 ([256 rows][32k] = 16KB)
        int row = gi >> 2;
        int k16 = (gi & 3) ^ ((row >> 1) & 3);
        gload_lds16(g + (row0 + row) * (long)ldk + col0 + k16 * 8,
                    region + r * 4096 + wbase);
    }
}

__device__ __forceinline__ f16x8 rd_frag(const char* region, int row, int l4) {
    int slot = l4 ^ ((row >> 1) & 3);
    return *(const f16x8*)(region + row * 64 + (slot << 4));
}

template <int EPI>
__global__ __launch_bounds__(256, 1) void gemm_bt(const unsigned short* __restrict__ A,
                                                  const unsigned short* __restrict__ BT,
                                                  const float* __restrict__ bias,
                                                  unsigned short* __restrict__ Cb,
                                                  float* __restrict__ pS,
                                                  int M, int N, int K) {
    __shared__ __align__(16) char lds[98304];   // 3 bufs x (16KB A + 16KB B)
    const int tid = threadIdx.x;
    const int lane = tid & 63;
    const int w = tid >> 6;
    const int wm = w >> 1, wn = w & 1;           // 2M x 2N, wave tile 128x128
    const int l15 = lane & 15, l4 = lane >> 4;

    // XCD-aware swizzle (nwg % 8 == 0 for our shapes)
    const int nwg = gridDim.x;
    const int cpx = nwg >> 3;
    const int bid = blockIdx.x;
    const int wg = (bid & 7) * cpx + (bid >> 3);
    const int ntn = N >> 8;
    const long bm = (long)(wg / ntn) * 256;
    const long bn = (long)(wg % ntn) * 256;

    const int NT = K >> 5;     // BK=32

    f32x4 acc[8][8];
#pragma unroll
    for (int i = 0; i < 8; ++i)
#pragma unroll
        for (int j = 0; j < 8; ++j) acc[i][j] = (f32x4){0.f, 0.f, 0.f, 0.f};

    // ---- prologue: stage t0 -> buf0, t1 -> buf1; retire t0 (8 loads of t1 in flight)
    stage_r(A, K, bm, 0, lds, tid);
    stage_r(BT, K, bn, 0, lds + 16384, tid);
    stage_r(A, K, bm, 32, lds + 32768, tid);
    stage_r(BT, K, bn, 32, lds + 32768 + 16384, tid);
    asm volatile("s_waitcnt vmcnt(8)" ::: "memory");
    __builtin_amdgcn_s_barrier();
    asm volatile("" ::: "memory");

    int cur = 0, nx2 = 2;
    for (int t = 0; t < NT; ++t) {
        const char* Ac = lds + cur * 32768;
        const char* Bc = Ac + 16384;
        f16x8 af[8], bv[8];
#pragma unroll
        for (int fn = 0; fn < 8; ++fn)
            bv[fn] = rd_frag(Bc, wn * 128 + fn * 16 + l15, l4);
#pragma unroll
        for (int fm = 0; fm < 8; ++fm)
            af[fm] = rd_frag(Ac, wm * 128 + fm * 16 + l15, l4);
        if (t + 2 < NT) {
            char* dst = lds + nx2 * 32768;
            stage_r(A, K, bm, (t + 2) * 32, dst, tid);
            stage_r(BT, K, bn, (t + 2) * 32, dst + 16384, tid);
        }
#pragma unroll
        for (int fm = 0; fm < 8; ++fm)
#pragma unroll
            for (int fn = 0; fn < 8; ++fn)
                acc[fm][fn] = __builtin_amdgcn_mfma_f32_16x16x32_f16(af[fm], bv[fn], acc[fm][fn], 0, 0, 0);
        if (t + 2 < NT) {
            asm volatile("s_waitcnt vmcnt(8)" ::: "memory");  // retire tile t+1
        } else if (t + 1 < NT) {
            asm volatile("s_waitcnt vmcnt(0)" ::: "memory");  // tail drain
        }
        __builtin_amdgcn_s_barrier();
        asm volatile("" ::: "memory");
        cur = (cur == 2) ? 0 : cur + 1;
        nx2 = (nx2 == 2) ? 0 : nx2 + 1;
    }

    // ---- epilogue: LDS-staged coalesced f16 C write, 4 quarters of 64 rows
    unsigned short* cl = (unsigned short*)lds;
    float cs[8], cq[8];
#pragma unroll
    for (int i = 0; i < 8; ++i) { cs[i] = 0.f; cq[i] = 0.f; }
#pragma unroll
    for (int q = 0; q < 4; ++q) {
        __syncthreads();
        if (wm == (q >> 1)) {
#pragma unroll
            for (int fn = 0; fn < 8; ++fn) {
                int col = wn * 128 + fn * 16 + l15;
                float bval = bias[bn + col];
#pragma unroll
                for (int fi = 0; fi < 4; ++fi) {
                    const int fm = (q & 1) * 4 + fi;
                    int rl = fi * 16 + l4 * 4;
#pragma unroll
                    for (int r = 0; r < 4; ++r) {
                        float v = acc[fm][fn][r] + bval;
                        if (EPI == 0) v = fmaxf(v, 0.f);
                        else { cs[fn] += v; cq[fn] += v * v; }
                        cl[(rl + r) * 264 + col] = f2h(v);
                    }
                }
            }
        }
        __syncthreads();
#pragma unroll
        for (int i = 0; i < 8; ++i) {
            int g = tid + i * 256;
            int r = g >> 5, cg = (g & 31) << 3;
            u16x8 val = *(const u16x8*)&cl[r * 264 + cg];
            *(u16x8*)&Cb[(bm + q * 64 + r) * N + bn + cg] = val;
        }
    }
    if (EPI == 1) {
#pragma unroll
        for (int fn = 0; fn < 8; ++fn) {
            float s = cs[fn], q = cq[fn];
            s += __shfl_xor(s, 16); s += __shfl_xor(s, 32);
            q += __shfl_xor(q, 16); q += __shfl_xor(q, 32);
            if (l4 == 0) {
                int col = (int)bn + wn * 128 + fn * 16 + l15;
                int rowgrp = ((int)(bm >> 8)) * 2 + wm;   // [0,512), 128-row groups
                pS[rowgrp * 512 + col] = s;
                pS[262144 + rowgrp * 512 + col] = q;
            }
        }
    }
}

// ---------------- BN reduce, 2-stage parallel (fixed order -> deterministic)
__global__ void k_bnA(const float* __restrict__ pS, float* __restrict__ pT) {
    int b = blockIdx.x;   // 64 blocks, 8 rowgrps each
    int t = threadIdx.x;  // 256
    float s0 = 0.f, s1 = 0.f, q0 = 0.f, q1 = 0.f;
#pragma unroll
    for (int i = 0; i < 8; ++i) {
        int rg = b * 8 + i;
        s0 += pS[rg * 512 + t];
        s1 += pS[rg * 512 + t + 256];
        q0 += pS[262144 + rg * 512 + t];
        q1 += pS[262144 + rg * 512 + t + 256];
    }
    pT[b * 512 + t] = s0;
    pT[b * 512 + t + 256] = s1;
    pT[32768 + b * 512 + t] = q0;
    pT[32768 + b * 512 + t + 256] = q1;
}

__global__ void k_bnB(const float* __restrict__ pT, const float* __restrict__ gamma,
                      const float* __restrict__ beta, float* __restrict__ ss) {
    int c = threadIdx.x;  // 512
    float s = 0.f, q = 0.f;
    for (int b = 0; b < 64; ++b) {
        s += pT[b * 512 + c];
        q += pT[32768 + b * 512 + c];
    }
    float mean = s * (1.f / (float)Nn);
    float var = q * (1.f / (float)Nn) - mean * mean;
    float a = gamma[c] * rsqrtf(var + EPSf);
    ss[c] = a;
    ss[512 + c] = beta[c] - mean * a;
}

// ---------------- final BN normalize (no relu): f16 hh -> f32 h (d_out)
__global__ void k_norm(const unsigned short* __restrict__ hhf, const float* __restrict__ ss,
                       float4* __restrict__ h4) {
    const int total = Nn * 128;
    const float4* ss4 = (const float4*)ss;
    for (int idx = blockIdx.x * blockDim.x + threadIdx.x; idx < total;
         idx += gridDim.x * blockDim.x) {
        int c = idx & 127;
        ushort4 u = *(const ushort4*)(hhf + (size_t)idx * 4);
        float4 v = make_float4(h2f(u.x), h2f(u.y), h2f(u.z), h2f(u.w));
        float4 a = ss4[c], b = ss4[128 + c];
        v.x = fmaf(v.x, a.x, b.x); v.y = fmaf(v.y, a.y, b.y);
        v.z = fmaf(v.z, a.z, b.z); v.w = fmaf(v.w, a.w, b.w);
        h4[idx] = v;
    }
}

// ---------------- graph mean pool: read f16 hh + fused BN affine (batch sorted)
__global__ void k_pool(const unsigned short* __restrict__ hhf, const float* __restrict__ ss,
                       const int* __restrict__ batch, float* __restrict__ graph) {
    int g = blockIdx.x, t = threadIdx.x;  // 512 blocks, 256 threads
    int lo = 0, hi = Nn;
    while (lo < hi) { int m = (lo + hi) >> 1; if (batch[m] < g) lo = m + 1; else hi = m; }
    int s = lo;
    lo = s; hi = Nn;
    while (lo < hi) { int m = (lo + hi) >> 1; if (batch[m] <= g) lo = m + 1; else hi = m; }
    int e = lo;
    float a0 = ss[t], a1 = ss[t + 256];
    float b0 = ss[512 + t], b1 = ss[512 + t + 256];
    float s0 = 0.f, s1 = 0.f;
    for (int r = s; r < e; ++r) {
        const unsigned short* row = hhf + (size_t)r * Dd;
        s0 += fmaf(h2f(row[t]), a0, b0);
        s1 += fmaf(h2f(row[t + 256]), a1, b1);
    }
    int cnt = e - s; if (cnt < 1) cnt = 1;
    float inv = 1.f / (float)cnt;
    graph[(long)g * Dd + t] = s0 * inv;
    graph[(long)g * Dd + t + 256] = s1 * inv;
}

extern "C" void kernel_launch(void* const* d_in, const int* in_sizes, int n_in,
                              void* d_out, int out_size, void* d_ws, size_t ws_size,
                              hipStream_t stream) {
    (void)in_sizes; (void)n_in; (void)out_size; (void)ws_size;
    const int* x      = (const int*)d_in[0];
    const int* ei     = (const int*)d_in[1];
    const int* ea     = (const int*)d_in[2];
    const int* batch  = (const int*)d_in[3];
    const float* xe1  = (const float*)d_in[4];
    const float* xe2  = (const float*)d_in[5];
    const float* ee1  = (const float*)d_in[6];
    const float* ee2  = (const float*)d_in[7];
    const float* W1   = (const float*)d_in[8];
    const float* b1   = (const float*)d_in[9];
    const float* W2   = (const float*)d_in[10];
    const float* b2   = (const float*)d_in[11];
    const float* gamma = (const float*)d_in[12];
    const float* beta  = (const float*)d_in[13];

    float* graph = (float*)d_out;
    float* h = graph + (size_t)Gg * Dd;  // N*D f32; aliased as hh1 f16 [N][2D]

    // d_ws layout (~143 MB): small/index arrays FIRST, then big buffers.
    char* w = (char*)d_ws;
    int* csr_off = (int*)w;                     w += (Nn + 1) * 4;
    int* cursor = (int*)w;                      w += Nn * 4;
    int* cnt = (int*)w;                         w += Nn * 4;
    int* ckey = (int*)w;                        w += Ee * 4;
    int* csrc = (int*)w;                        w += Ee * 4;
    float* ss = (float*)w;                      w += 4096;
    float* pS = (float*)w;                      w += 2 * 512 * 512 * 4;     // BN partials, 2 MB
    float* pT = (float*)w;                      w += 2 * 64 * 512 * 4;      // BN stage-2, 256 KB
    float* Etab = (float*)w;                    w += (size_t)Ll * 18 * Dd * 4;  // 184 KB
    unsigned short* aggh = (unsigned short*)w;  w += (size_t)Nn * Dd * 2;   // agg f16, 64 MB
    unsigned short* hhf = (unsigned short*)w;   w += (size_t)Nn * Dd * 2;   // hh f16, 64 MB
    unsigned short* w1t = (unsigned short*)w;   w += (size_t)Ll * D2 * Dd * 2;
    unsigned short* w2t = (unsigned short*)w;   w += (size_t)Ll * Dd * D2 * 2;

    // weights -> f16 transposed [N][K]; edge-emb table; atom embedding (f16 h0)
    k_transW<<<2048, 256, 0, stream>>>(W1, w1t, Dd, D2);
    k_transW<<<2048, 256, 0, stream>>>(W2, w2t, D2, Dd);
    k_etab<<<(Ll * 18 * Dd + 255) / 256, 256, 0, stream>>>(ee1, ee2, Etab);
    k_embed<<<2048, 256, 0, stream>>>(x, xe1, xe2, hhf);

    // CSR build (topology constant across layers); sorted -> bit-deterministic
    k_zeroN<<<64, 1024, 0, stream>>>(cnt, Nn);
    k_hist<<<Ee / 256, 256, 0, stream>>>(ei + Ee, cnt);
    k_scan<<<1, 1024, 0, stream>>>(cnt, csr_off, cursor);
    k_place<<<Ee / 256, 256, 0, stream>>>(ei, ei + Ee, ea, cursor, ckey, csrc);
    k_sort<<<Nn / 256, 256, 0, stream>>>(csr_off, ckey, csrc);

    for (int l = 0; l < Ll; ++l) {
        const float* El = Etab + (size_t)l * 18 * Dd;
        if (l == 0)
            k_gather<0><<<Nn / 4, 256, 0, stream>>>(hhf, nullptr, csr_off, ckey, csrc,
                                                    El, aggh);
        else
            k_gather<1><<<Nn / 4, 256, 0, stream>>>(hhf, ss, csr_off, ckey, csrc,
                                                    El, aggh);
        gemm_bt<0><<<(Nn / 256) * (D2 / 256), 256, 0, stream>>>(
            aggh, w1t + (size_t)l * D2 * Dd, b1 + (size_t)l * D2,
            (unsigned short*)h, nullptr, Nn, D2, Dd);
        gemm_bt<1><<<(Nn / 256) * (Dd / 256), 256, 0, stream>>>(
            (const unsigned short*)h, w2t + (size_t)l * Dd * D2, b2 + (size_t)l * Dd,
            hhf, pS, Nn, Dd, D2);
        k_bnA<<<64, 256, 0, stream>>>(pS, pT);
        k_bnB<<<1, 512, 0, stream>>>(pT, gamma + (size_t)l * Dd, beta + (size_t)l * Dd, ss);
    }

    // final-layer BN (no relu) -> h f32, then pool (pool reads f16 hh directly)
    k_norm<<<2048, 256, 0, stream>>>(hhf, ss, (float4*)h);
    k_pool<<<Gg, 256, 0, stream>>>(hhf, ss, batch, graph);
}

// Round 14
// 1436.707 us; speedup vs baseline: 1.5836x; 1.0906x over previous
//
#include <hip/hip_runtime.h>
#include <stdint.h>

#define Nn 65536
#define Ee 131072
#define Dd 512
#define D2 1024
#define Ll 5
#define Gg 512
#define EPSf 1e-5f

typedef _Float16 f16x8 __attribute__((ext_vector_type(8)));
typedef float f32x4 __attribute__((ext_vector_type(4)));
typedef unsigned short u16x8 __attribute__((ext_vector_type(8)));

__device__ __forceinline__ unsigned short f2h(float f) {
    _Float16 h = (_Float16)f;  // v_cvt_f16_f32, RNE
    union { _Float16 h; unsigned short u; } c; c.h = h;
    return c.u;
}

__device__ __forceinline__ float h2f(unsigned short s) {
    union { unsigned short s; _Float16 h; } c; c.s = s;
    return (float)c.h;
}

__device__ __forceinline__ void gload_lds16(const void* g, void* l) {
    __builtin_amdgcn_global_load_lds(
        (const __attribute__((address_space(1))) void*)(uintptr_t)g,
        (__attribute__((address_space(3))) void*)(unsigned)(uintptr_t)l,
        16, 0, 0);
}

// ---------------- weight transpose: src [L][K][Nw] f32 -> dst [L][Nw][K] f16
__global__ void k_transW(const float* __restrict__ src, unsigned short* __restrict__ dst,
                         int K, int Nw) {
    long total = (long)Ll * K * Nw;
    for (long idx = (long)blockIdx.x * blockDim.x + threadIdx.x; idx < total;
         idx += (long)gridDim.x * blockDim.x) {
        long l = idx / ((long)K * Nw);
        long rem = idx - l * (long)K * Nw;
        int k = (int)(rem / Nw), n = (int)(rem % Nw);
        dst[(l * Nw + n) * K + k] = f2h(src[idx]);
    }
}

// ---------------- edge-embedding table: E[l][18][512] = ee1[l][j/3] + ee2[l][j%3]
__global__ void k_etab(const float* __restrict__ ee1, const float* __restrict__ ee2,
                       float* __restrict__ E) {
    int idx = blockIdx.x * blockDim.x + threadIdx.x;
    const int total = Ll * 18 * Dd;
    if (idx < total) {
        int l = idx / (18 * Dd);
        int rem = idx - l * 18 * Dd;
        int j = rem / Dd, c = rem - j * Dd;
        int a0 = j / 3, a1 = j - a0 * 3;
        E[idx] = ee1[((size_t)l * 6 + a0) * Dd + c] + ee2[((size_t)l * 3 + a1) * Dd + c];
    }
}

// ---------------- atom embedding -> f16 h0 (into hhf)
__global__ void k_embed(const int* __restrict__ x,
                        const float* __restrict__ xe1, const float* __restrict__ xe2,
                        unsigned short* __restrict__ hhf) {
    const int total = Nn * 64;
    for (int idx = blockIdx.x * blockDim.x + threadIdx.x; idx < total;
         idx += gridDim.x * blockDim.x) {
        int node = idx >> 6, c8 = (idx & 63) * 8;
        int t0 = x[2 * node], t1 = x[2 * node + 1];
        const float4* p1 = (const float4*)(xe1 + (size_t)t0 * Dd + c8);
        const float4* p2 = (const float4*)(xe2 + (size_t)t1 * Dd + c8);
        float4 a0 = p1[0], a1 = p1[1], b0 = p2[0], b1 = p2[1];
        u16x8 o;
        o[0] = f2h(a0.x + b0.x); o[1] = f2h(a0.y + b0.y);
        o[2] = f2h(a0.z + b0.z); o[3] = f2h(a0.w + b0.w);
        o[4] = f2h(a1.x + b1.x); o[5] = f2h(a1.y + b1.y);
        o[6] = f2h(a1.z + b1.z); o[7] = f2h(a1.w + b1.w);
        *(u16x8*)(hhf + (size_t)node * Dd + c8) = o;
    }
}

// ---------------- CSR build (dst-sorted), deterministic after k_sort
__global__ void k_zeroN(int* __restrict__ p, int n) {
    int i = blockIdx.x * blockDim.x + threadIdx.x;
    if (i < n) p[i] = 0;
}

__global__ void k_hist(const int* __restrict__ edst, int* __restrict__ cnt) {
    int e = blockIdx.x * blockDim.x + threadIdx.x;
    if (e < Ee) atomicAdd(&cnt[edst[e]], 1);
}

__global__ void k_scan(const int* __restrict__ cnt, int* __restrict__ off,
                       int* __restrict__ cursor) {
    __shared__ int part[1024];
    int t = threadIdx.x;
    int base = t * 64;
    int s = 0;
    for (int i = 0; i < 64; ++i) s += cnt[base + i];
    part[t] = s;
    __syncthreads();
    for (int d = 1; d < 1024; d <<= 1) {
        int v = (t >= d) ? part[t - d] : 0;
        __syncthreads();
        part[t] += v;
        __syncthreads();
    }
    int run = part[t] - s;  // exclusive prefix
    for (int i = 0; i < 64; ++i) {
        off[base + i] = run;
        cursor[base + i] = run;
        run += cnt[base + i];
    }
    if (t == 1023) off[Nn] = run;
}

// key = edge_idx*32 + attr (attr = a0*3+a1 in 0..8); unique keys
__global__ void k_place(const int* __restrict__ esrc, const int* __restrict__ edst,
                        const int* __restrict__ eattr, int* __restrict__ cursor,
                        int* __restrict__ ckey, int* __restrict__ csrc) {
    int e = blockIdx.x * blockDim.x + threadIdx.x;
    if (e < Ee) {
        int d = edst[e];
        int p = atomicAdd(&cursor[d], 1);
        ckey[p] = e * 32 + (eattr[2 * e] * 3 + eattr[2 * e + 1]);
        csrc[p] = esrc[e];
    }
}

// per-node insertion sort by key -> CSR bit-identical on every call
__global__ void k_sort(const int* __restrict__ off, int* __restrict__ ckey,
                       int* __restrict__ csrc) {
    int node = blockIdx.x * blockDim.x + threadIdx.x;
    if (node >= Nn) return;
    int kb = off[node], ke = off[node + 1];
    for (int i = kb + 1; i < ke; ++i) {
        int k = ckey[i], s = csrc[i];
        int j = i - 1;
        while (j >= kb && ckey[j] > k) {
            ckey[j + 1] = ckey[j]; csrc[j + 1] = csrc[j]; --j;
        }
        ckey[j + 1] = k; csrc[j + 1] = s;
    }
}

// ---------------- gather: agg[n] = act(h[n]) + E[12] + sum_e (act(h[src]) + E[attr]) -> f16
template <int NORM>
__global__ __launch_bounds__(256) void k_gather(const unsigned short* __restrict__ hf16,
                                                const float* __restrict__ ss,
                                                const int* __restrict__ off,
                                                const int* __restrict__ ckey,
                                                const int* __restrict__ csrc,
                                                const float* __restrict__ El,
                                                unsigned short* __restrict__ aggh) {
    int node = (blockIdx.x << 2) + (threadIdx.x >> 6);
    int lane = threadIdx.x & 63;
    int c8 = lane * 8;
    float sa[8], sb[8];
    if (NORM) {
        float4 a0 = *(const float4*)(ss + c8), a1 = *(const float4*)(ss + c8 + 4);
        float4 b0 = *(const float4*)(ss + 512 + c8), b1 = *(const float4*)(ss + 512 + c8 + 4);
        sa[0] = a0.x; sa[1] = a0.y; sa[2] = a0.z; sa[3] = a0.w;
        sa[4] = a1.x; sa[5] = a1.y; sa[6] = a1.z; sa[7] = a1.w;
        sb[0] = b0.x; sb[1] = b0.y; sb[2] = b0.z; sb[3] = b0.w;
        sb[4] = b1.x; sb[5] = b1.y; sb[6] = b1.z; sb[7] = b1.w;
    }
    float acc[8];
    {
        u16x8 v = *(const u16x8*)(hf16 + (size_t)node * Dd + c8);
        float4 e0 = *(const float4*)(El + 12 * Dd + c8);
        float4 e1 = *(const float4*)(El + 12 * Dd + c8 + 4);
        float ev[8];
        ev[0] = e0.x; ev[1] = e0.y; ev[2] = e0.z; ev[3] = e0.w;
        ev[4] = e1.x; ev[5] = e1.y; ev[6] = e1.z; ev[7] = e1.w;
#pragma unroll
        for (int i = 0; i < 8; ++i) {
            float hv = h2f(v[i]);
            if (NORM) hv = fmaxf(fmaf(hv, sa[i], sb[i]), 0.f);
            acc[i] = hv + ev[i];
        }
    }
    int kb = off[node], ke = off[node + 1];
    for (int k = kb; k < ke; ++k) {
        int src = csrc[k];
        int at = ckey[k] & 31;
        u16x8 v = *(const u16x8*)(hf16 + (size_t)src * Dd + c8);
        const float* Er = El + (size_t)at * Dd + c8;
        float4 e0 = *(const float4*)(Er);
        float4 e1 = *(const float4*)(Er + 4);
        float ev[8];
        ev[0] = e0.x; ev[1] = e0.y; ev[2] = e0.z; ev[3] = e0.w;
        ev[4] = e1.x; ev[5] = e1.y; ev[6] = e1.z; ev[7] = e1.w;
#pragma unroll
        for (int i = 0; i < 8; ++i) {
            float hv = h2f(v[i]);
            if (NORM) hv = fmaxf(fmaf(hv, sa[i], sb[i]), 0.f);
            acc[i] += hv + ev[i];
        }
    }
    u16x8 o;
#pragma unroll
    for (int i = 0; i < 8; ++i) o[i] = f2h(acc[i]);
    *(u16x8*)(aggh + (size_t)node * Dd + c8) = o;
}

// ================ deep-prefetch GEMM: 256x256 tile, 8 waves (2M x 4N), BK=32,
// 4 LDS parities (128KB), staged 3 tiles ahead, exact-counted vmcnt per tile.
// Same barrier cadence / ds_read count / wave split / acc size as the r11 gemm8;
// only the stage-issue -> retire distance grows (1 -> 3 sub-phases, ~2000 cyc).
__device__ __forceinline__ void stage_h(const unsigned short* __restrict__ g, int ldk,
                                        long row0, int col0, char* region, int tid) {
    int wbase = (tid >> 6) << 10;  // wave * 1024 bytes
#pragma unroll
    for (int r = 0; r < 2; ++r) {
        int gi = tid + r * 512;            // granule 0..1023 ([256 rows][32k] = 16KB)
        int row = gi >> 2;
        int k16 = (gi & 3) ^ ((row >> 1) & 3);
        gload_lds16(g + (row0 + row) * (long)ldk + col0 + k16 * 8,
                    region + r * 8192 + wbase);
    }
}

__device__ __forceinline__ f16x8 rd_frag(const char* region, int row, int l4) {
    int slot = l4 ^ ((row >> 1) & 3);
    return *(const f16x8*)(region + row * 64 + (slot << 4));
}

template <int EPI>
__global__ __launch_bounds__(512, 2) void gemm_dp(const unsigned short* __restrict__ A,
                                                  const unsigned short* __restrict__ BT,
                                                  const float* __restrict__ bias,
                                                  unsigned short* __restrict__ Cb,
                                                  float* __restrict__ pS,
                                                  int M, int N, int K) {
    __shared__ __align__(16) char lds[131072];   // 4 parities x (16KB A + 16KB B)
    const int tid = threadIdx.x;
    const int lane = tid & 63;
    const int w = tid >> 6;
    const int wm = w >> 2, wn = w & 3;
    const int l15 = lane & 15, l4 = lane >> 4;

    // XCD-aware swizzle (nwg % 8 == 0 for our shapes)
    const int nwg = gridDim.x;
    const int cpx = nwg >> 3;
    const int bid = blockIdx.x;
    const int wg = (bid & 7) * cpx + (bid >> 3);
    const int ntn = N >> 8;
    const long bm = (long)(wg / ntn) * 256;
    const long bn = (long)(wg % ntn) * 256;

    const int NT = K >> 5;     // BK=32; parity p = t&3 at lds + p*32768 (A), +16384 (B)

    f32x4 acc[8][4];
#pragma unroll
    for (int i = 0; i < 8; ++i)
#pragma unroll
        for (int j = 0; j < 4; ++j) acc[i][j] = (f32x4){0.f, 0.f, 0.f, 0.f};

    // ---- prologue: stage t0,t1,t2 (4 loads/thread each); retire t0
    stage_h(A, K, bm, 0, lds, tid);
    stage_h(BT, K, bn, 0, lds + 16384, tid);
    stage_h(A, K, bm, 32, lds + 32768, tid);
    stage_h(BT, K, bn, 32, lds + 32768 + 16384, tid);
    stage_h(A, K, bm, 64, lds + 65536, tid);
    stage_h(BT, K, bn, 64, lds + 65536 + 16384, tid);
    asm volatile("s_waitcnt vmcnt(8)" ::: "memory");
    __builtin_amdgcn_s_barrier();
    asm volatile("" ::: "memory");

    for (int t = 0; t < NT; ++t) {
        const char* Ac = lds + (size_t)(t & 3) * 32768;
        const char* Bc = Ac + 16384;
        f16x8 af[8], bv[4];
        // bv first: MFMA[0][*] unblocks after 5 reads, not 12
#pragma unroll
        for (int fn = 0; fn < 4; ++fn)
            bv[fn] = rd_frag(Bc, wn * 64 + fn * 16 + l15, l4);
#pragma unroll
        for (int fm = 0; fm < 8; ++fm)
            af[fm] = rd_frag(Ac, wm * 128 + fm * 16 + l15, l4);
        if (t + 3 < NT) {
            char* dst = lds + (size_t)((t + 3) & 3) * 32768;
            stage_h(A, K, bm, (t + 3) * 32, dst, tid);
            stage_h(BT, K, bn, (t + 3) * 32, dst + 16384, tid);
        }
#pragma unroll
        for (int fm = 0; fm < 8; ++fm)
#pragma unroll
            for (int fn = 0; fn < 4; ++fn)
                acc[fm][fn] = __builtin_amdgcn_mfma_f32_16x16x32_f16(af[fm], bv[fn], acc[fm][fn], 0, 0, 0);
        // exact-counted retire of tile t+1 (4 loads/thread per tile):
        if (t + 3 < NT) {
            asm volatile("s_waitcnt vmcnt(8)" ::: "memory");   // t+2,t+3 may remain
        } else if (t + 2 < NT) {
            asm volatile("s_waitcnt vmcnt(4)" ::: "memory");   // t+2 may remain
        } else if (t + 1 < NT) {
            asm volatile("s_waitcnt vmcnt(0)" ::: "memory");   // drain t+1
        }
        __builtin_amdgcn_s_barrier();
        asm volatile("" ::: "memory");
    }

    // ---- epilogue: LDS-staged coalesced f16 C write (+stats for EPI 1)
    unsigned short* cl = (unsigned short*)lds;
    float cs[4] = {0.f, 0.f, 0.f, 0.f}, cq[4] = {0.f, 0.f, 0.f, 0.f};
#pragma unroll
    for (int hh = 0; hh < 2; ++hh) {
        __syncthreads();
        if (wm == hh) {
#pragma unroll
            for (int fn = 0; fn < 4; ++fn) {
                int col = wn * 64 + fn * 16 + l15;
                float bval = bias[bn + col];
#pragma unroll
                for (int fm = 0; fm < 8; ++fm) {
                    int r0 = fm * 16 + l4 * 4;
#pragma unroll
                    for (int r = 0; r < 4; ++r) {
                        float v = acc[fm][fn][r] + bval;
                        if (EPI == 0) v = fmaxf(v, 0.f);
                        else { cs[fn] += v; cq[fn] += v * v; }
                        cl[(r0 + r) * 264 + col] = f2h(v);
                    }
                }
            }
        }
        __syncthreads();
#pragma unroll
        for (int i = 0; i < 8; ++i) {
            int g = tid + i * 512;
            int r = g >> 5, cg = (g & 31) << 3;
            u16x8 val = *(const u16x8*)&cl[r * 264 + cg];
            *(u16x8*)&Cb[(bm + hh * 128 + r) * N + bn + cg] = val;
        }
    }
    if (EPI == 1) {
#pragma unroll
        for (int fn = 0; fn < 4; ++fn) {
            float s = cs[fn], q = cq[fn];
            s += __shfl_xor(s, 16); s += __shfl_xor(s, 32);
            q += __shfl_xor(q, 16); q += __shfl_xor(q, 32);
            if (l4 == 0) {
                int col = (int)bn + wn * 64 + fn * 16 + l15;
                int rowgrp = ((int)(bm >> 8)) * 2 + wm;   // [0,512), 128-row groups
                pS[rowgrp * 512 + col] = s;
                pS[262144 + rowgrp * 512 + col] = q;
            }
        }
    }
}

// ---------------- BN reduce, 2-stage parallel (fixed order -> deterministic)
__global__ void k_bnA(const float* __restrict__ pS, float* __restrict__ pT) {
    int b = blockIdx.x;   // 64 blocks, 8 rowgrps each
    int t = threadIdx.x;  // 256
    float s0 = 0.f, s1 = 0.f, q0 = 0.f, q1 = 0.f;
#pragma unroll
    for (int i = 0; i < 8; ++i) {
        int rg = b * 8 + i;
        s0 += pS[rg * 512 + t];
        s1 += pS[rg * 512 + t + 256];
        q0 += pS[262144 + rg * 512 + t];
        q1 += pS[262144 + rg * 512 + t + 256];
    }
    pT[b * 512 + t] = s0;
    pT[b * 512 + t + 256] = s1;
    pT[32768 + b * 512 + t] = q0;
    pT[32768 + b * 512 + t + 256] = q1;
}

__global__ void k_bnB(const float* __restrict__ pT, const float* __restrict__ gamma,
                      const float* __restrict__ beta, float* __restrict__ ss) {
    int c = threadIdx.x;  // 512
    float s = 0.f, q = 0.f;
    for (int b = 0; b < 64; ++b) {
        s += pT[b * 512 + c];
        q += pT[32768 + b * 512 + c];
    }
    float mean = s * (1.f / (float)Nn);
    float var = q * (1.f / (float)Nn) - mean * mean;
    float a = gamma[c] * rsqrtf(var + EPSf);
    ss[c] = a;
    ss[512 + c] = beta[c] - mean * a;
}

// ---------------- final BN normalize (no relu): f16 hh -> f32 h (d_out)
__global__ void k_norm(const unsigned short* __restrict__ hhf, const float* __restrict__ ss,
                       float4* __restrict__ h4) {
    const int total = Nn * 128;
    const float4* ss4 = (const float4*)ss;
    for (int idx = blockIdx.x * blockDim.x + threadIdx.x; idx < total;
         idx += gridDim.x * blockDim.x) {
        int c = idx & 127;
        ushort4 u = *(const ushort4*)(hhf + (size_t)idx * 4);
        float4 v = make_float4(h2f(u.x), h2f(u.y), h2f(u.z), h2f(u.w));
        float4 a = ss4[c], b = ss4[128 + c];
        v.x = fmaf(v.x, a.x, b.x); v.y = fmaf(v.y, a.y, b.y);
        v.z = fmaf(v.z, a.z, b.z); v.w = fmaf(v.w, a.w, b.w);
        h4[idx] = v;
    }
}

// ---------------- graph mean pool: read f16 hh + fused BN affine (batch sorted)
__global__ void k_pool(const unsigned short* __restrict__ hhf, const float* __restrict__ ss,
                       const int* __restrict__ batch, float* __restrict__ graph) {
    int g = blockIdx.x, t = threadIdx.x;  // 512 blocks, 256 threads
    int lo = 0, hi = Nn;
    while (lo < hi) { int m = (lo + hi) >> 1; if (batch[m] < g) lo = m + 1; else hi = m; }
    int s = lo;
    lo = s; hi = Nn;
    while (lo < hi) { int m = (lo + hi) >> 1; if (batch[m] <= g) lo = m + 1; else hi = m; }
    int e = lo;
    float a0 = ss[t], a1 = ss[t + 256];
    float b0 = ss[512 + t], b1 = ss[512 + t + 256];
    float s0 = 0.f, s1 = 0.f;
    for (int r = s; r < e; ++r) {
        const unsigned short* row = hhf + (size_t)r * Dd;
        s0 += fmaf(h2f(row[t]), a0, b0);
        s1 += fmaf(h2f(row[t + 256]), a1, b1);
    }
    int cnt = e - s; if (cnt < 1) cnt = 1;
    float inv = 1.f / (float)cnt;
    graph[(long)g * Dd + t] = s0 * inv;
    graph[(long)g * Dd + t + 256] = s1 * inv;
}

extern "C" void kernel_launch(void* const* d_in, const int* in_sizes, int n_in,
                              void* d_out, int out_size, void* d_ws, size_t ws_size,
                              hipStream_t stream) {
    (void)in_sizes; (void)n_in; (void)out_size; (void)ws_size;
    const int* x      = (const int*)d_in[0];
    const int* ei     = (const int*)d_in[1];
    const int* ea     = (const int*)d_in[2];
    const int* batch  = (const int*)d_in[3];
    const float* xe1  = (const float*)d_in[4];
    const float* xe2  = (const float*)d_in[5];
    const float* ee1  = (const float*)d_in[6];
    const float* ee2  = (const float*)d_in[7];
    const float* W1   = (const float*)d_in[8];
    const float* b1   = (const float*)d_in[9];
    const float* W2   = (const float*)d_in[10];
    const float* b2   = (const float*)d_in[11];
    const float* gamma = (const float*)d_in[12];
    const float* beta  = (const float*)d_in[13];

    float* graph = (float*)d_out;
    float* h = graph + (size_t)Gg * Dd;  // N*D f32; aliased as hh1 f16 [N][2D]

    // d_ws layout (~143 MB): small/index arrays FIRST, then big buffers.
    char* w = (char*)d_ws;
    int* csr_off = (int*)w;                     w += (Nn + 1) * 4;
    int* cursor = (int*)w;                      w += Nn * 4;
    int* cnt = (int*)w;                         w += Nn * 4;
    int* ckey = (int*)w;                        w += Ee * 4;
    int* csrc = (int*)w;                        w += Ee * 4;
    float* ss = (float*)w;                      w += 4096;
    float* pS = (float*)w;                      w += 2 * 512 * 512 * 4;     // BN partials, 2 MB
    float* pT = (float*)w;                      w += 2 * 64 * 512 * 4;      // BN stage-2, 256 KB
    float* Etab = (float*)w;                    w += (size_t)Ll * 18 * Dd * 4;  // 184 KB
    unsigned short* aggh = (unsigned short*)w;  w += (size_t)Nn * Dd * 2;   // agg f16, 64 MB
    unsigned short* hhf = (unsigned short*)w;   w += (size_t)Nn * Dd * 2;   // hh f16, 64 MB
    unsigned short* w1t = (unsigned short*)w;   w += (size_t)Ll * D2 * Dd * 2;
    unsigned short* w2t = (unsigned short*)w;   w += (size_t)Ll * Dd * D2 * 2;

    // weights -> f16 transposed [N][K]; edge-emb table; atom embedding (f16 h0)
    k_transW<<<2048, 256, 0, stream>>>(W1, w1t, Dd, D2);
    k_transW<<<2048, 256, 0, stream>>>(W2, w2t, D2, Dd);
    k_etab<<<(Ll * 18 * Dd + 255) / 256, 256, 0, stream>>>(ee1, ee2, Etab);
    k_embed<<<2048, 256, 0, stream>>>(x, xe1, xe2, hhf);

    // CSR build (topology constant across layers); sorted -> bit-deterministic
    k_zeroN<<<64, 1024, 0, stream>>>(cnt, Nn);
    k_hist<<<Ee / 256, 256, 0, stream>>>(ei + Ee, cnt);
    k_scan<<<1, 1024, 0, stream>>>(cnt, csr_off, cursor);
    k_place<<<Ee / 256, 256, 0, stream>>>(ei, ei + Ee, ea, cursor, ckey, csrc);
    k_sort<<<Nn / 256, 256, 0, stream>>>(csr_off, ckey, csrc);

    for (int l = 0; l < Ll; ++l) {
        const float* El = Etab + (size_t)l * 18 * Dd;
        if (l == 0)
            k_gather<0><<<Nn / 4, 256, 0, stream>>>(hhf, nullptr, csr_off, ckey, csrc,
                                                    El, aggh);
        else
            k_gather<1><<<Nn / 4, 256, 0, stream>>>(hhf, ss, csr_off, ckey, csrc,
                                                    El, aggh);
        gemm_dp<0><<<(Nn / 256) * (D2 / 256), 512, 0, stream>>>(
            aggh, w1t + (size_t)l * D2 * Dd, b1 + (size_t)l * D2,
            (unsigned short*)h, nullptr, Nn, D2, Dd);
        gemm_dp<1><<<(Nn / 256) * (Dd / 256), 512, 0, stream>>>(
            (const unsigned short*)h, w2t + (size_t)l * Dd * D2, b2 + (size_t)l * Dd,
            hhf, pS, Nn, Dd, D2);
        k_bnA<<<64, 256, 0, stream>>>(pS, pT);
        k_bnB<<<1, 512, 0, stream>>>(pT, gamma + (size_t)l * Dd, beta + (size_t)l * Dd, ss);
    }

    // final-layer BN (no relu) -> h f32, then pool (pool reads f16 hh directly)
    k_norm<<<2048, 256, 0, stream>>>(hhf, ss, (float4*)h);
    k_pool<<<Gg, 256, 0, stream>>>(hhf, ss, batch, graph);
}

// Round 15
// 1415.227 us; speedup vs baseline: 1.6076x; 1.0152x over previous
//
#include <hip/hip_runtime.h>
#include <stdint.h>

#define Nn 65536
#define Ee 131072
#define Dd 512
#define D2 1024
#define Ll 5
#define Gg 512
#define EPSf 1e-5f

typedef _Float16 f16x8 __attribute__((ext_vector_type(8)));
typedef float f32x4 __attribute__((ext_vector_type(4)));
typedef unsigned short u16x8 __attribute__((ext_vector_type(8)));

__device__ __forceinline__ unsigned short f2h(float f) {
    _Float16 h = (_Float16)f;  // v_cvt_f16_f32, RNE
    union { _Float16 h; unsigned short u; } c; c.h = h;
    return c.u;
}

__device__ __forceinline__ float h2f(unsigned short s) {
    union { unsigned short s; _Float16 h; } c; c.s = s;
    return (float)c.h;
}

__device__ __forceinline__ void gload_lds16(const void* g, void* l) {
    __builtin_amdgcn_global_load_lds(
        (const __attribute__((address_space(1))) void*)(uintptr_t)g,
        (__attribute__((address_space(3))) void*)(unsigned)(uintptr_t)l,
        16, 0, 0);
}

// ---------------- weight pack: src [L][K][Nw] f32 -> MFMA-fragment layout f16
// dst frag (n16, k32): [l][n>>4][k>>5][lane][e], lane=(n&15)+(((k>>3)&3)<<4), e=k&7
// -> a wave's B fragment = ONE coalesced 1KB read at base + lane*16B.
__global__ void k_packW(const float* __restrict__ src, unsigned short* __restrict__ dst,
                        int K, int Nw) {
    long total = (long)Ll * K * Nw;
    int KF = K >> 5, NF = Nw >> 4;
    for (long idx = (long)blockIdx.x * blockDim.x + threadIdx.x; idx < total;
         idx += (long)gridDim.x * blockDim.x) {
        long l = idx / ((long)K * Nw);
        long rem = idx - l * (long)K * Nw;
        int k = (int)(rem / Nw), n = (int)(rem % Nw);
        int lane = (n & 15) + (((k >> 3) & 3) << 4);
        long di = (((l * NF + (n >> 4)) * KF + (k >> 5)) * 64 + lane) * 8 + (k & 7);
        dst[di] = f2h(src[idx]);
    }
}

// ---------------- edge-embedding table: E[l][18][512] = ee1[l][j/3] + ee2[l][j%3]
__global__ void k_etab(const float* __restrict__ ee1, const float* __restrict__ ee2,
                       float* __restrict__ E) {
    int idx = blockIdx.x * blockDim.x + threadIdx.x;
    const int total = Ll * 18 * Dd;
    if (idx < total) {
        int l = idx / (18 * Dd);
        int rem = idx - l * 18 * Dd;
        int j = rem / Dd, c = rem - j * Dd;
        int a0 = j / 3, a1 = j - a0 * 3;
        E[idx] = ee1[((size_t)l * 6 + a0) * Dd + c] + ee2[((size_t)l * 3 + a1) * Dd + c];
    }
}

// ---------------- atom embedding -> f16 h0 (into hhf)
__global__ void k_embed(const int* __restrict__ x,
                        const float* __restrict__ xe1, const float* __restrict__ xe2,
                        unsigned short* __restrict__ hhf) {
    const int total = Nn * 64;
    for (int idx = blockIdx.x * blockDim.x + threadIdx.x; idx < total;
         idx += gridDim.x * blockDim.x) {
        int node = idx >> 6, c8 = (idx & 63) * 8;
        int t0 = x[2 * node], t1 = x[2 * node + 1];
        const float4* p1 = (const float4*)(xe1 + (size_t)t0 * Dd + c8);
        const float4* p2 = (const float4*)(xe2 + (size_t)t1 * Dd + c8);
        float4 a0 = p1[0], a1 = p1[1], b0 = p2[0], b1 = p2[1];
        u16x8 o;
        o[0] = f2h(a0.x + b0.x); o[1] = f2h(a0.y + b0.y);
        o[2] = f2h(a0.z + b0.z); o[3] = f2h(a0.w + b0.w);
        o[4] = f2h(a1.x + b1.x); o[5] = f2h(a1.y + b1.y);
        o[6] = f2h(a1.z + b1.z); o[7] = f2h(a1.w + b1.w);
        *(u16x8*)(hhf + (size_t)node * Dd + c8) = o;
    }
}

// ---------------- CSR build (dst-sorted), deterministic after k_sort
__global__ void k_zeroN(int* __restrict__ p, int n) {
    int i = blockIdx.x * blockDim.x + threadIdx.x;
    if (i < n) p[i] = 0;
}

__global__ void k_hist(const int* __restrict__ edst, int* __restrict__ cnt) {
    int e = blockIdx.x * blockDim.x + threadIdx.x;
    if (e < Ee) atomicAdd(&cnt[edst[e]], 1);
}

__global__ void k_scan(const int* __restrict__ cnt, int* __restrict__ off,
                       int* __restrict__ cursor) {
    __shared__ int part[1024];
    int t = threadIdx.x;
    int base = t * 64;
    int s = 0;
    for (int i = 0; i < 64; ++i) s += cnt[base + i];
    part[t] = s;
    __syncthreads();
    for (int d = 1; d < 1024; d <<= 1) {
        int v = (t >= d) ? part[t - d] : 0;
        __syncthreads();
        part[t] += v;
        __syncthreads();
    }
    int run = part[t] - s;  // exclusive prefix
    for (int i = 0; i < 64; ++i) {
        off[base + i] = run;
        cursor[base + i] = run;
        run += cnt[base + i];
    }
    if (t == 1023) off[Nn] = run;
}

// key = edge_idx*32 + attr (attr = a0*3+a1 in 0..8); unique keys
__global__ void k_place(const int* __restrict__ esrc, const int* __restrict__ edst,
                        const int* __restrict__ eattr, int* __restrict__ cursor,
                        int* __restrict__ ckey, int* __restrict__ csrc) {
    int e = blockIdx.x * blockDim.x + threadIdx.x;
    if (e < Ee) {
        int d = edst[e];
        int p = atomicAdd(&cursor[d], 1);
        ckey[p] = e * 32 + (eattr[2 * e] * 3 + eattr[2 * e + 1]);
        csrc[p] = esrc[e];
    }
}

// per-node insertion sort by key -> CSR bit-identical on every call
__global__ void k_sort(const int* __restrict__ off, int* __restrict__ ckey,
                       int* __restrict__ csrc) {
    int node = blockIdx.x * blockDim.x + threadIdx.x;
    if (node >= Nn) return;
    int kb = off[node], ke = off[node + 1];
    for (int i = kb + 1; i < ke; ++i) {
        int k = ckey[i], s = csrc[i];
        int j = i - 1;
        while (j >= kb && ckey[j] > k) {
            ckey[j + 1] = ckey[j]; csrc[j + 1] = csrc[j]; --j;
        }
        ckey[j + 1] = k; csrc[j + 1] = s;
    }
}

// ---------------- gather: agg[n] = act(h[n]) + E[12] + sum_e (act(h[src]) + E[attr]) -> f16
template <int NORM>
__global__ __launch_bounds__(256) void k_gather(const unsigned short* __restrict__ hf16,
                                                const float* __restrict__ ss,
                                                const int* __restrict__ off,
                                                const int* __restrict__ ckey,
                                                const int* __restrict__ csrc,
                                                const float* __restrict__ El,
                                                unsigned short* __restrict__ aggh) {
    int node = (blockIdx.x << 2) + (threadIdx.x >> 6);
    int lane = threadIdx.x & 63;
    int c8 = lane * 8;
    float sa[8], sb[8];
    if (NORM) {
        float4 a0 = *(const float4*)(ss + c8), a1 = *(const float4*)(ss + c8 + 4);
        float4 b0 = *(const float4*)(ss + 512 + c8), b1 = *(const float4*)(ss + 512 + c8 + 4);
        sa[0] = a0.x; sa[1] = a0.y; sa[2] = a0.z; sa[3] = a0.w;
        sa[4] = a1.x; sa[5] = a1.y; sa[6] = a1.z; sa[7] = a1.w;
        sb[0] = b0.x; sb[1] = b0.y; sb[2] = b0.z; sb[3] = b0.w;
        sb[4] = b1.x; sb[5] = b1.y; sb[6] = b1.z; sb[7] = b1.w;
    }
    float acc[8];
    {
        u16x8 v = *(const u16x8*)(hf16 + (size_t)node * Dd + c8);
        float4 e0 = *(const float4*)(El + 12 * Dd + c8);
        float4 e1 = *(const float4*)(El + 12 * Dd + c8 + 4);
        float ev[8];
        ev[0] = e0.x; ev[1] = e0.y; ev[2] = e0.z; ev[3] = e0.w;
        ev[4] = e1.x; ev[5] = e1.y; ev[6] = e1.z; ev[7] = e1.w;
#pragma unroll
        for (int i = 0; i < 8; ++i) {
            float hv = h2f(v[i]);
            if (NORM) hv = fmaxf(fmaf(hv, sa[i], sb[i]), 0.f);
            acc[i] = hv + ev[i];
        }
    }
    int kb = off[node], ke = off[node + 1];
    for (int k = kb; k < ke; ++k) {
        int src = csrc[k];
        int at = ckey[k] & 31;
        u16x8 v = *(const u16x8*)(hf16 + (size_t)src * Dd + c8);
        const float* Er = El + (size_t)at * Dd + c8;
        float4 e0 = *(const float4*)(Er);
        float4 e1 = *(const float4*)(Er + 4);
        float ev[8];
        ev[0] = e0.x; ev[1] = e0.y; ev[2] = e0.z; ev[3] = e0.w;
        ev[4] = e1.x; ev[5] = e1.y; ev[6] = e1.z; ev[7] = e1.w;
#pragma unroll
        for (int i = 0; i < 8; ++i) {
            float hv = h2f(v[i]);
            if (NORM) hv = fmaxf(fmaf(hv, sa[i], sb[i]), 0.f);
            acc[i] += hv + ev[i];
        }
    }
    u16x8 o;
#pragma unroll
    for (int i = 0; i < 8; ++i) o[i] = f2h(acc[i]);
    *(u16x8*)(aggh + (size_t)node * Dd + c8) = o;
}

// ================ GEMM: r11 structure, but B DIRECT from fragment-packed global.
// 256x256 tile, 8 waves (2M x 4N), BK=64, 2 kh sub-phases per tile.
// LDS holds A ONLY: 4 regions (2 parity x 2 kh) x 16KB. B fragment = one
// coalesced 1KB L1/L2 read (pre-packed). LDS read traffic/K-tile 192->128KB.
// No manual vmcnt in loop: compiler's bv-wait drains older A-stages (in-order).
__device__ __forceinline__ void stage_q(const unsigned short* __restrict__ g, int ldk,
                                        long row0, int col0, char* region, int tid) {
    int wbase = (tid >> 6) << 10;  // wave * 1024 bytes
#pragma unroll
    for (int r = 0; r < 2; ++r) {
        int gi = tid + r * 512;            // granule 0..1023
        int row = gi >> 2;
        int k16 = (gi & 3) ^ ((row >> 1) & 3);
        gload_lds16(g + (row0 + row) * (long)ldk + col0 + k16 * 8,
                    region + r * 8192 + wbase);
    }
}

__device__ __forceinline__ f16x8 rd_frag(const char* region, int row, int l4) {
    int slot = l4 ^ ((row >> 1) & 3);
    return *(const f16x8*)(region + row * 64 + (slot << 4));
}

template <int EPI>
__global__ __launch_bounds__(512, 2) void gemm_bp(const unsigned short* __restrict__ A,
                                                  const unsigned short* __restrict__ BP,
                                                  const float* __restrict__ bias,
                                                  unsigned short* __restrict__ Cb,
                                                  float* __restrict__ pS,
                                                  int M, int N, int K) {
    __shared__ __align__(16) char lds[131072];   // first 64KB: A regions; epilogue reuses
    const int tid = threadIdx.x;
    const int lane = tid & 63;
    const int w = tid >> 6;
    const int wm = w >> 2, wn = w & 3;
    const int l15 = lane & 15, l4 = lane >> 4;

    // XCD-aware swizzle (nwg % 8 == 0 for our shapes)
    const int nwg = gridDim.x;
    const int cpx = nwg >> 3;
    const int bid = blockIdx.x;
    const int wg = (bid & 7) * cpx + (bid >> 3);
    const int ntn = N >> 8;
    const long bm = (long)(wg / ntn) * 256;
    const long bn = (long)(wg % ntn) * 256;

    char* Ar = lds;            // region(par, kh) = Ar + par*32768 + kh*16384
    const int NT = K >> 6;     // BK=64
    const int KF = K >> 5;     // fragment-k count
    // B fragment base for this wave: frag rows bn/16 + wn*4 + fn
    const unsigned short* Bw = BP + ((size_t)((int)(bn >> 4) + wn * 4) * KF) * 512 + lane * 8;

    f32x4 acc[8][4];
#pragma unroll
    for (int i = 0; i < 8; ++i)
#pragma unroll
        for (int j = 0; j < 4; ++j) acc[i][j] = (f32x4){0.f, 0.f, 0.f, 0.f};

    // ---- prologue: stage A t0 kh0, kh1; retire kh0
    stage_q(A, K, bm, 0, Ar, tid);
    stage_q(A, K, bm, 32, Ar + 16384, tid);
    asm volatile("s_waitcnt vmcnt(2)" ::: "memory");
    __builtin_amdgcn_s_barrier();
    asm volatile("" ::: "memory");

    for (int t = 0; t < NT; ++t) {
        const int par = (t & 1) << 15;
        const int npar = ((t + 1) & 1) << 15;
        const bool pre = (t + 1 < NT);
#pragma unroll
        for (int kh = 0; kh < 2; ++kh) {
            const char* Ac = Ar + par + kh * 16384;
            const int kf = (t << 1) + kh;
            f16x8 af[8], bv[4];
            // bv: 4 coalesced 1KB fragment loads (L1/L2) — issued FIRST so the
            // compiler's bv-wait also retires all older A-stages (in-order count).
#pragma unroll
            for (int fn = 0; fn < 4; ++fn)
                bv[fn] = *(const f16x8*)(Bw + ((size_t)fn * KF + kf) * 512);
#pragma unroll
            for (int fm = 0; fm < 8; ++fm)
                af[fm] = rd_frag(Ac, wm * 128 + fm * 16 + l15, l4);
            if (pre)
                stage_q(A, K, bm, (t + 1) * 64 + kh * 32, Ar + npar + kh * 16384, tid);
#pragma unroll
            for (int fm = 0; fm < 8; ++fm)
#pragma unroll
                for (int fn = 0; fn < 4; ++fn)
                    acc[fm][fn] = __builtin_amdgcn_mfma_f32_16x16x32_f16(af[fm], bv[fn], acc[fm][fn], 0, 0, 0);
            __builtin_amdgcn_s_barrier();
            asm volatile("" ::: "memory");
        }
    }

    // ---- epilogue: LDS-staged coalesced f16 C write (+stats for EPI 1)
    unsigned short* cl = (unsigned short*)lds;
    float cs[4] = {0.f, 0.f, 0.f, 0.f}, cq[4] = {0.f, 0.f, 0.f, 0.f};
#pragma unroll
    for (int hh = 0; hh < 2; ++hh) {
        __syncthreads();
        if (wm == hh) {
#pragma unroll
            for (int fn = 0; fn < 4; ++fn) {
                int col = wn * 64 + fn * 16 + l15;
                float bval = bias[bn + col];
#pragma unroll
                for (int fm = 0; fm < 8; ++fm) {
                    int r0 = fm * 16 + l4 * 4;
#pragma unroll
                    for (int r = 0; r < 4; ++r) {
                        float v = acc[fm][fn][r] + bval;
                        if (EPI == 0) v = fmaxf(v, 0.f);
                        else { cs[fn] += v; cq[fn] += v * v; }
                        cl[(r0 + r) * 264 + col] = f2h(v);
                    }
                }
            }
        }
        __syncthreads();
#pragma unroll
        for (int i = 0; i < 8; ++i) {
            int g = tid + i * 512;
            int r = g >> 5, cg = (g & 31) << 3;
            u16x8 val = *(const u16x8*)&cl[r * 264 + cg];
            *(u16x8*)&Cb[(bm + hh * 128 + r) * N + bn + cg] = val;
        }
    }
    if (EPI == 1) {
#pragma unroll
        for (int fn = 0; fn < 4; ++fn) {
            float s = cs[fn], q = cq[fn];
            s += __shfl_xor(s, 16); s += __shfl_xor(s, 32);
            q += __shfl_xor(q, 16); q += __shfl_xor(q, 32);
            if (l4 == 0) {
                int col = (int)bn + wn * 64 + fn * 16 + l15;
                int rowgrp = ((int)(bm >> 8)) * 2 + wm;   // [0,512), 128-row groups
                pS[rowgrp * 512 + col] = s;
                pS[262144 + rowgrp * 512 + col] = q;
            }
        }
    }
}

// ---------------- BN reduce, 2-stage parallel (fixed order -> deterministic)
__global__ void k_bnA(const float* __restrict__ pS, float* __restrict__ pT) {
    int b = blockIdx.x;   // 64 blocks, 8 rowgrps each
    int t = threadIdx.x;  // 256
    float s0 = 0.f, s1 = 0.f, q0 = 0.f, q1 = 0.f;
#pragma unroll
    for (int i = 0; i < 8; ++i) {
        int rg = b * 8 + i;
        s0 += pS[rg * 512 + t];
        s1 += pS[rg * 512 + t + 256];
        q0 += pS[262144 + rg * 512 + t];
        q1 += pS[262144 + rg * 512 + t + 256];
    }
    pT[b * 512 + t] = s0;
    pT[b * 512 + t + 256] = s1;
    pT[32768 + b * 512 + t] = q0;
    pT[32768 + b * 512 + t + 256] = q1;
}

__global__ void k_bnB(const float* __restrict__ pT, const float* __restrict__ gamma,
                      const float* __restrict__ beta, float* __restrict__ ss) {
    int c = threadIdx.x;  // 512
    float s = 0.f, q = 0.f;
    for (int b = 0; b < 64; ++b) {
        s += pT[b * 512 + c];
        q += pT[32768 + b * 512 + c];
    }
    float mean = s * (1.f / (float)Nn);
    float var = q * (1.f / (float)Nn) - mean * mean;
    float a = gamma[c] * rsqrtf(var + EPSf);
    ss[c] = a;
    ss[512 + c] = beta[c] - mean * a;
}

// ---------------- final BN normalize (no relu): f16 hh -> f32 h (d_out)
__global__ void k_norm(const unsigned short* __restrict__ hhf, const float* __restrict__ ss,
                       float4* __restrict__ h4) {
    const int total = Nn * 128;
    const float4* ss4 = (const float4*)ss;
    for (int idx = blockIdx.x * blockDim.x + threadIdx.x; idx < total;
         idx += gridDim.x * blockDim.x) {
        int c = idx & 127;
        ushort4 u = *(const ushort4*)(hhf + (size_t)idx * 4);
        float4 v = make_float4(h2f(u.x), h2f(u.y), h2f(u.z), h2f(u.w));
        float4 a = ss4[c], b = ss4[128 + c];
        v.x = fmaf(v.x, a.x, b.x); v.y = fmaf(v.y, a.y, b.y);
        v.z = fmaf(v.z, a.z, b.z); v.w = fmaf(v.w, a.w, b.w);
        h4[idx] = v;
    }
}

// ---------------- graph mean pool: read f16 hh + fused BN affine (batch sorted)
__global__ void k_pool(const unsigned short* __restrict__ hhf, const float* __restrict__ ss,
                       const int* __restrict__ batch, float* __restrict__ graph) {
    int g = blockIdx.x, t = threadIdx.x;  // 512 blocks, 256 threads
    int lo = 0, hi = Nn;
    while (lo < hi) { int m = (lo + hi) >> 1; if (batch[m] < g) lo = m + 1; else hi = m; }
    int s = lo;
    lo = s; hi = Nn;
    while (lo < hi) { int m = (lo + hi) >> 1; if (batch[m] <= g) lo = m + 1; else hi = m; }
    int e = lo;
    float a0 = ss[t], a1 = ss[t + 256];
    float b0 = ss[512 + t], b1 = ss[512 + t + 256];
    float s0 = 0.f, s1 = 0.f;
    for (int r = s; r < e; ++r) {
        const unsigned short* row = hhf + (size_t)r * Dd;
        s0 += fmaf(h2f(row[t]), a0, b0);
        s1 += fmaf(h2f(row[t + 256]), a1, b1);
    }
    int cnt = e - s; if (cnt < 1) cnt = 1;
    float inv = 1.f / (float)cnt;
    graph[(long)g * Dd + t] = s0 * inv;
    graph[(long)g * Dd + t + 256] = s1 * inv;
}

extern "C" void kernel_launch(void* const* d_in, const int* in_sizes, int n_in,
                              void* d_out, int out_size, void* d_ws, size_t ws_size,
                              hipStream_t stream) {
    (void)in_sizes; (void)n_in; (void)out_size; (void)ws_size;
    const int* x      = (const int*)d_in[0];
    const int* ei     = (const int*)d_in[1];
    const int* ea     = (const int*)d_in[2];
    const int* batch  = (const int*)d_in[3];
    const float* xe1  = (const float*)d_in[4];
    const float* xe2  = (const float*)d_in[5];
    const float* ee1  = (const float*)d_in[6];
    const float* ee2  = (const float*)d_in[7];
    const float* W1   = (const float*)d_in[8];
    const float* b1   = (const float*)d_in[9];
    const float* W2   = (const float*)d_in[10];
    const float* b2   = (const float*)d_in[11];
    const float* gamma = (const float*)d_in[12];
    const float* beta  = (const float*)d_in[13];

    float* graph = (float*)d_out;
    float* h = graph + (size_t)Gg * Dd;  // N*D f32; aliased as hh1 f16 [N][2D]

    // d_ws layout (~143 MB): small/index arrays FIRST, then big buffers.
    char* w = (char*)d_ws;
    int* csr_off = (int*)w;                     w += (Nn + 1) * 4;
    int* cursor = (int*)w;                      w += Nn * 4;
    int* cnt = (int*)w;                         w += Nn * 4;
    int* ckey = (int*)w;                        w += Ee * 4;
    int* csrc = (int*)w;                        w += Ee * 4;
    float* ss = (float*)w;                      w += 4096;
    float* pS = (float*)w;                      w += 2 * 512 * 512 * 4;     // BN partials, 2 MB
    float* pT = (float*)w;                      w += 2 * 64 * 512 * 4;      // BN stage-2, 256 KB
    float* Etab = (float*)w;                    w += (size_t)Ll * 18 * Dd * 4;  // 184 KB
    unsigned short* aggh = (unsigned short*)w;  w += (size_t)Nn * Dd * 2;   // agg f16, 64 MB
    unsigned short* hhf = (unsigned short*)w;   w += (size_t)Nn * Dd * 2;   // hh f16, 64 MB
    unsigned short* w1p = (unsigned short*)w;   w += (size_t)Ll * D2 * Dd * 2;
    unsigned short* w2p = (unsigned short*)w;   w += (size_t)Ll * Dd * D2 * 2;

    // weights -> fragment-packed f16; edge-emb table; atom embedding (f16 h0)
    k_packW<<<2048, 256, 0, stream>>>(W1, w1p, Dd, D2);
    k_packW<<<2048, 256, 0, stream>>>(W2, w2p, D2, Dd);
    k_etab<<<(Ll * 18 * Dd + 255) / 256, 256, 0, stream>>>(ee1, ee2, Etab);
    k_embed<<<2048, 256, 0, stream>>>(x, xe1, xe2, hhf);

    // CSR build (topology constant across layers); sorted -> bit-deterministic
    k_zeroN<<<64, 1024, 0, stream>>>(cnt, Nn);
    k_hist<<<Ee / 256, 256, 0, stream>>>(ei + Ee, cnt);
    k_scan<<<1, 1024, 0, stream>>>(cnt, csr_off, cursor);
    k_place<<<Ee / 256, 256, 0, stream>>>(ei, ei + Ee, ea, cursor, ckey, csrc);
    k_sort<<<Nn / 256, 256, 0, stream>>>(csr_off, ckey, csrc);

    for (int l = 0; l < Ll; ++l) {
        const float* El = Etab + (size_t)l * 18 * Dd;
        if (l == 0)
            k_gather<0><<<Nn / 4, 256, 0, stream>>>(hhf, nullptr, csr_off, ckey, csrc,
                                                    El, aggh);
        else
            k_gather<1><<<Nn / 4, 256, 0, stream>>>(hhf, ss, csr_off, ckey, csrc,
                                                    El, aggh);
        gemm_bp<0><<<(Nn / 256) * (D2 / 256), 512, 0, stream>>>(
            aggh, w1p + (size_t)l * D2 * Dd, b1 + (size_t)l * D2,
            (unsigned short*)h, nullptr, Nn, D2, Dd);
        gemm_bp<1><<<(Nn / 256) * (Dd / 256), 512, 0, stream>>>(
            (const unsigned short*)h, w2p + (size_t)l * Dd * D2, b2 + (size_t)l * Dd,
            hhf, pS, Nn, Dd, D2);
        k_bnA<<<64, 256, 0, stream>>>(pS, pT);
        k_bnB<<<1, 512, 0, stream>>>(pT, gamma + (size_t)l * Dd, beta + (size_t)l * Dd, ss);
    }

    // final-layer BN (no relu) -> h f32, then pool (pool reads f16 hh directly)
    k_norm<<<2048, 256, 0, stream>>>(hhf, ss, (float4*)h);
    k_pool<<<Gg, 256, 0, stream>>>(hhf, ss, batch, graph);
}

// Round 16
// 1413.076 us; speedup vs baseline: 1.6101x; 1.0015x over previous
//
#include <hip/hip_runtime.h>
#include <stdint.h>

#define Nn 65536
#define Ee 131072
#define Dd 512
#define D2 1024
#define Ll 5
#define Gg 512
#define EPSf 1e-5f

typedef _Float16 f16x8 __attribute__((ext_vector_type(8)));
typedef float f32x4 __attribute__((ext_vector_type(4)));
typedef unsigned short u16x8 __attribute__((ext_vector_type(8)));

__device__ __forceinline__ unsigned short f2h(float f) {
    _Float16 h = (_Float16)f;  // v_cvt_f16_f32, RNE
    union { _Float16 h; unsigned short u; } c; c.h = h;
    return c.u;
}

__device__ __forceinline__ float h2f(unsigned short s) {
    union { unsigned short s; _Float16 h; } c; c.s = s;
    return (float)c.h;
}

__device__ __forceinline__ void gload_lds16(const void* g, void* l) {
    __builtin_amdgcn_global_load_lds(
        (const __attribute__((address_space(1))) void*)(uintptr_t)g,
        (__attribute__((address_space(3))) void*)(unsigned)(uintptr_t)l,
        16, 0, 0);
}

// ---------------- weight transpose: src [L][K][Nw] f32 -> dst [L][Nw][K] f16
__global__ void k_transW(const float* __restrict__ src, unsigned short* __restrict__ dst,
                         int K, int Nw) {
    long total = (long)Ll * K * Nw;
    for (long idx = (long)blockIdx.x * blockDim.x + threadIdx.x; idx < total;
         idx += (long)gridDim.x * blockDim.x) {
        long l = idx / ((long)K * Nw);
        long rem = idx - l * (long)K * Nw;
        int k = (int)(rem / Nw), n = (int)(rem % Nw);
        dst[(l * Nw + n) * K + k] = f2h(src[idx]);
    }
}

// ---------------- edge-embedding table: E[l][18][512] = ee1[l][j/3] + ee2[l][j%3]
__global__ void k_etab(const float* __restrict__ ee1, const float* __restrict__ ee2,
                       float* __restrict__ E) {
    int idx = blockIdx.x * blockDim.x + threadIdx.x;
    const int total = Ll * 18 * Dd;
    if (idx < total) {
        int l = idx / (18 * Dd);
        int rem = idx - l * 18 * Dd;
        int j = rem / Dd, c = rem - j * Dd;
        int a0 = j / 3, a1 = j - a0 * 3;
        E[idx] = ee1[((size_t)l * 6 + a0) * Dd + c] + ee2[((size_t)l * 3 + a1) * Dd + c];
    }
}

// ---------------- atom embedding -> f16 h0 (into hhf)
__global__ void k_embed(const int* __restrict__ x,
                        const float* __restrict__ xe1, const float* __restrict__ xe2,
                        unsigned short* __restrict__ hhf) {
    const int total = Nn * 64;
    for (int idx = blockIdx.x * blockDim.x + threadIdx.x; idx < total;
         idx += gridDim.x * blockDim.x) {
        int node = idx >> 6, c8 = (idx & 63) * 8;
        int t0 = x[2 * node], t1 = x[2 * node + 1];
        const float4* p1 = (const float4*)(xe1 + (size_t)t0 * Dd + c8);
        const float4* p2 = (const float4*)(xe2 + (size_t)t1 * Dd + c8);
        float4 a0 = p1[0], a1 = p1[1], b0 = p2[0], b1 = p2[1];
        u16x8 o;
        o[0] = f2h(a0.x + b0.x); o[1] = f2h(a0.y + b0.y);
        o[2] = f2h(a0.z + b0.z); o[3] = f2h(a0.w + b0.w);
        o[4] = f2h(a1.x + b1.x); o[5] = f2h(a1.y + b1.y);
        o[6] = f2h(a1.z + b1.z); o[7] = f2h(a1.w + b1.w);
        *(u16x8*)(hhf + (size_t)node * Dd + c8) = o;
    }
}

// ---------------- CSR build (dst-sorted), deterministic after k_sort
__global__ void k_zeroN(int* __restrict__ p, int n) {
    int i = blockIdx.x * blockDim.x + threadIdx.x;
    if (i < n) p[i] = 0;
}

__global__ void k_hist(const int* __restrict__ edst, int* __restrict__ cnt) {
    int e = blockIdx.x * blockDim.x + threadIdx.x;
    if (e < Ee) atomicAdd(&cnt[edst[e]], 1);
}

__global__ void k_scan(const int* __restrict__ cnt, int* __restrict__ off,
                       int* __restrict__ cursor) {
    __shared__ int part[1024];
    int t = threadIdx.x;
    int base = t * 64;
    int s = 0;
    for (int i = 0; i < 64; ++i) s += cnt[base + i];
    part[t] = s;
    __syncthreads();
    for (int d = 1; d < 1024; d <<= 1) {
        int v = (t >= d) ? part[t - d] : 0;
        __syncthreads();
        part[t] += v;
        __syncthreads();
    }
    int run = part[t] - s;  // exclusive prefix
    for (int i = 0; i < 64; ++i) {
        off[base + i] = run;
        cursor[base + i] = run;
        run += cnt[base + i];
    }
    if (t == 1023) off[Nn] = run;
}

// key = edge_idx*32 + attr (attr = a0*3+a1 in 0..8); unique keys
__global__ void k_place(const int* __restrict__ esrc, const int* __restrict__ edst,
                        const int* __restrict__ eattr, int* __restrict__ cursor,
                        int* __restrict__ ckey, int* __restrict__ csrc) {
    int e = blockIdx.x * blockDim.x + threadIdx.x;
    if (e < Ee) {
        int d = edst[e];
        int p = atomicAdd(&cursor[d], 1);
        ckey[p] = e * 32 + (eattr[2 * e] * 3 + eattr[2 * e + 1]);
        csrc[p] = esrc[e];
    }
}

// per-node insertion sort by key -> CSR bit-identical on every call
__global__ void k_sort(const int* __restrict__ off, int* __restrict__ ckey,
                       int* __restrict__ csrc) {
    int node = blockIdx.x * blockDim.x + threadIdx.x;
    if (node >= Nn) return;
    int kb = off[node], ke = off[node + 1];
    for (int i = kb + 1; i < ke; ++i) {
        int k = ckey[i], s = csrc[i];
        int j = i - 1;
        while (j >= kb && ckey[j] > k) {
            ckey[j + 1] = ckey[j]; csrc[j + 1] = csrc[j]; --j;
        }
        ckey[j + 1] = k; csrc[j + 1] = s;
    }
}

// ---------------- gather: agg[n] = act(h[n]) + E[12] + sum_e (act(h[src]) + E[attr]) -> f16
template <int NORM>
__global__ __launch_bounds__(256) void k_gather(const unsigned short* __restrict__ hf16,
                                                const float* __restrict__ ss,
                                                const int* __restrict__ off,
                                                const int* __restrict__ ckey,
                                                const int* __restrict__ csrc,
                                                const float* __restrict__ El,
                                                unsigned short* __restrict__ aggh) {
    int node = (blockIdx.x << 2) + (threadIdx.x >> 6);
    int lane = threadIdx.x & 63;
    int c8 = lane * 8;
    float sa[8], sb[8];
    if (NORM) {
        float4 a0 = *(const float4*)(ss + c8), a1 = *(const float4*)(ss + c8 + 4);
        float4 b0 = *(const float4*)(ss + 512 + c8), b1 = *(const float4*)(ss + 512 + c8 + 4);
        sa[0] = a0.x; sa[1] = a0.y; sa[2] = a0.z; sa[3] = a0.w;
        sa[4] = a1.x; sa[5] = a1.y; sa[6] = a1.z; sa[7] = a1.w;
        sb[0] = b0.x; sb[1] = b0.y; sb[2] = b0.z; sb[3] = b0.w;
        sb[4] = b1.x; sb[5] = b1.y; sb[6] = b1.z; sb[7] = b1.w;
    }
    float acc[8];
    {
        u16x8 v = *(const u16x8*)(hf16 + (size_t)node * Dd + c8);
        float4 e0 = *(const float4*)(El + 12 * Dd + c8);
        float4 e1 = *(const float4*)(El + 12 * Dd + c8 + 4);
        float ev[8];
        ev[0] = e0.x; ev[1] = e0.y; ev[2] = e0.z; ev[3] = e0.w;
        ev[4] = e1.x; ev[5] = e1.y; ev[6] = e1.z; ev[7] = e1.w;
#pragma unroll
        for (int i = 0; i < 8; ++i) {
            float hv = h2f(v[i]);
            if (NORM) hv = fmaxf(fmaf(hv, sa[i], sb[i]), 0.f);
            acc[i] = hv + ev[i];
        }
    }
    int kb = off[node], ke = off[node + 1];
    for (int k = kb; k < ke; ++k) {
        int src = csrc[k];
        int at = ckey[k] & 31;
        u16x8 v = *(const u16x8*)(hf16 + (size_t)src * Dd + c8);
        const float* Er = El + (size_t)at * Dd + c8;
        float4 e0 = *(const float4*)(Er);
        float4 e1 = *(const float4*)(Er + 4);
        float ev[8];
        ev[0] = e0.x; ev[1] = e0.y; ev[2] = e0.z; ev[3] = e0.w;
        ev[4] = e1.x; ev[5] = e1.y; ev[6] = e1.z; ev[7] = e1.w;
#pragma unroll
        for (int i = 0; i < 8; ++i) {
            float hv = h2f(v[i]);
            if (NORM) hv = fmaxf(fmaf(hv, sa[i], sb[i]), 0.f);
            acc[i] += hv + ev[i];
        }
    }
    u16x8 o;
#pragma unroll
    for (int i = 0; i < 8; ++i) o[i] = f2h(acc[i]);
    *(u16x8*)(aggh + (size_t)node * Dd + c8) = o;
}

// ================ overlap GEMM: 256x128 tile, 4 waves (2M x 2N, wave 128x64),
// BK=32, 3-parity LDS (72KB: A 16KB + B 8KB per parity), staged 2 tiles ahead,
// vmcnt(6) per tile. 232 regs/wave + 72KB -> TWO blocks/CU: two independent
// barrier domains, each block's barrier/LDS stall filled by the other (m114).
// FLOP/LDS-byte identical to the 256x256 8-wave config (375 B/MFMA-inst).
__device__ __forceinline__ void stage_a(const unsigned short* __restrict__ g, int ldk,
                                        long row0, int col0, char* region, int tid) {
    int wbase = (tid >> 6) << 10;  // wave * 1024 bytes
#pragma unroll
    for (int r = 0; r < 4; ++r) {
        int gi = tid + r * 256;            // 1024 granules = 256 rows x 32k
        int row = gi >> 2;
        int k16 = (gi & 3) ^ ((row >> 1) & 3);
        gload_lds16(g + (row0 + row) * (long)ldk + col0 + k16 * 8,
                    region + r * 4096 + wbase);
    }
}

__device__ __forceinline__ void stage_b(const unsigned short* __restrict__ g, int ldk,
                                        long row0, int col0, char* region, int tid) {
    int wbase = (tid >> 6) << 10;
#pragma unroll
    for (int r = 0; r < 2; ++r) {
        int gi = tid + r * 256;            // 512 granules = 128 rows x 32k
        int row = gi >> 2;
        int k16 = (gi & 3) ^ ((row >> 1) & 3);
        gload_lds16(g + (row0 + row) * (long)ldk + col0 + k16 * 8,
                    region + r * 4096 + wbase);
    }
}

__device__ __forceinline__ f16x8 rd_frag(const char* region, int row, int l4) {
    int slot = l4 ^ ((row >> 1) & 3);
    return *(const f16x8*)(region + row * 64 + (slot << 4));
}

template <int EPI>
__global__ __launch_bounds__(256, 2) void gemm_ov(const unsigned short* __restrict__ A,
                                                  const unsigned short* __restrict__ BT,
                                                  const float* __restrict__ bias,
                                                  unsigned short* __restrict__ Cb,
                                                  float* __restrict__ pS,
                                                  int M, int N, int K) {
    __shared__ __align__(16) char lds[73728];   // 3 parities x 24KB
    const int tid = threadIdx.x;
    const int lane = tid & 63;
    const int w = tid >> 6;
    const int wm = w >> 1, wn = w & 1;          // 2M x 2N, wave tile 128x64
    const int l15 = lane & 15, l4 = lane >> 4;

    // XCD-aware swizzle (nwg % 8 == 0 for our shapes)
    const int nwg = gridDim.x;
    const int cpx = nwg >> 3;
    const int bid = blockIdx.x;
    const int wg = (bid & 7) * cpx + (bid >> 3);
    const int ntn = N >> 7;
    const long bm = (long)(wg / ntn) * 256;
    const long bn = (long)(wg % ntn) * 128;

    const int NT = K >> 5;     // BK=32

    f32x4 acc[8][4];
#pragma unroll
    for (int i = 0; i < 8; ++i)
#pragma unroll
        for (int j = 0; j < 4; ++j) acc[i][j] = (f32x4){0.f, 0.f, 0.f, 0.f};

    // ---- prologue: stage t0 -> par0, t1 -> par1 (6 gloads/thread each); retire t0
    stage_a(A, K, bm, 0, lds, tid);
    stage_b(BT, K, bn, 0, lds + 16384, tid);
    stage_a(A, K, bm, 32, lds + 24576, tid);
    stage_b(BT, K, bn, 32, lds + 24576 + 16384, tid);
    asm volatile("s_waitcnt vmcnt(6)" ::: "memory");
    __builtin_amdgcn_s_barrier();
    asm volatile("" ::: "memory");

    int cur = 0, nx2 = 2;      // compute parity; stage target = (cur+2)%3
    for (int t = 0; t < NT; ++t) {
        const char* Ac = lds + cur * 24576;
        const char* Bc = Ac + 16384;
        f16x8 af[8], bv[4];
#pragma unroll
        for (int fn = 0; fn < 4; ++fn)
            bv[fn] = rd_frag(Bc, wn * 64 + fn * 16 + l15, l4);
#pragma unroll
        for (int fm = 0; fm < 8; ++fm)
            af[fm] = rd_frag(Ac, wm * 128 + fm * 16 + l15, l4);
        if (t + 2 < NT) {
            char* dst = lds + nx2 * 24576;
            stage_a(A, K, bm, (t + 2) * 32, dst, tid);
            stage_b(BT, K, bn, (t + 2) * 32, dst + 16384, tid);
        }
#pragma unroll
        for (int fm = 0; fm < 8; ++fm)
#pragma unroll
            for (int fn = 0; fn < 4; ++fn)
                acc[fm][fn] = __builtin_amdgcn_mfma_f32_16x16x32_f16(af[fm], bv[fn], acc[fm][fn], 0, 0, 0);
        // retire tile t+1's 6 loads (issued one tile back); keep t+2's in flight
        if (t + 2 < NT) {
            asm volatile("s_waitcnt vmcnt(6)" ::: "memory");
        } else if (t + 1 < NT) {
            asm volatile("s_waitcnt vmcnt(0)" ::: "memory");
        }
        __builtin_amdgcn_s_barrier();
        asm volatile("" ::: "memory");
        cur = (cur == 2) ? 0 : cur + 1;
        nx2 = (nx2 == 2) ? 0 : nx2 + 1;
    }

    // ---- epilogue: single-pass LDS-staged coalesced f16 C write (68KB <= 72KB)
    unsigned short* cl = (unsigned short*)lds;
    float cs[4] = {0.f, 0.f, 0.f, 0.f}, cq[4] = {0.f, 0.f, 0.f, 0.f};
    __syncthreads();
#pragma unroll
    for (int fn = 0; fn < 4; ++fn) {
        int col = wn * 64 + fn * 16 + l15;
        float bval = bias[bn + col];
#pragma unroll
        for (int fm = 0; fm < 8; ++fm) {
            int r0 = wm * 128 + fm * 16 + l4 * 4;
#pragma unroll
            for (int r = 0; r < 4; ++r) {
                float v = acc[fm][fn][r] + bval;
                if (EPI == 0) v = fmaxf(v, 0.f);
                else { cs[fn] += v; cq[fn] += v * v; }
                cl[(r0 + r) * 136 + col] = f2h(v);
            }
        }
    }
    __syncthreads();
#pragma unroll
    for (int i = 0; i < 16; ++i) {
        int g = tid + i * 256;
        int r = g >> 4, cg = (g & 15) << 3;
        u16x8 val = *(const u16x8*)&cl[r * 136 + cg];
        *(u16x8*)&Cb[(bm + r) * N + bn + cg] = val;
    }
    if (EPI == 1) {
#pragma unroll
        for (int fn = 0; fn < 4; ++fn) {
            float s = cs[fn], q = cq[fn];
            s += __shfl_xor(s, 16); s += __shfl_xor(s, 32);
            q += __shfl_xor(q, 16); q += __shfl_xor(q, 32);
            if (l4 == 0) {
                int col = (int)bn + wn * 64 + fn * 16 + l15;
                int rowgrp = (int)(bm >> 7) + wm;   // [0,512), 128-row groups
                pS[rowgrp * 512 + col] = s;
                pS[262144 + rowgrp * 512 + col] = q;
            }
        }
    }
}

// ---------------- BN reduce, 2-stage parallel (fixed order -> deterministic)
__global__ void k_bnA(const float* __restrict__ pS, float* __restrict__ pT) {
    int b = blockIdx.x;   // 64 blocks, 8 rowgrps each
    int t = threadIdx.x;  // 256
    float s0 = 0.f, s1 = 0.f, q0 = 0.f, q1 = 0.f;
#pragma unroll
    for (int i = 0; i < 8; ++i) {
        int rg = b * 8 + i;
        s0 += pS[rg * 512 + t];
        s1 += pS[rg * 512 + t + 256];
        q0 += pS[262144 + rg * 512 + t];
        q1 += pS[262144 + rg * 512 + t + 256];
    }
    pT[b * 512 + t] = s0;
    pT[b * 512 + t + 256] = s1;
    pT[32768 + b * 512 + t] = q0;
    pT[32768 + b * 512 + t + 256] = q1;
}

__global__ void k_bnB(const float* __restrict__ pT, const float* __restrict__ gamma,
                      const float* __restrict__ beta, float* __restrict__ ss) {
    int c = threadIdx.x;  // 512
    float s = 0.f, q = 0.f;
    for (int b = 0; b < 64; ++b) {
        s += pT[b * 512 + c];
        q += pT[32768 + b * 512 + c];
    }
    float mean = s * (1.f / (float)Nn);
    float var = q * (1.f / (float)Nn) - mean * mean;
    float a = gamma[c] * rsqrtf(var + EPSf);
    ss[c] = a;
    ss[512 + c] = beta[c] - mean * a;
}

// ---------------- final BN normalize (no relu): f16 hh -> f32 h (d_out)
__global__ void k_norm(const unsigned short* __restrict__ hhf, const float* __restrict__ ss,
                       float4* __restrict__ h4) {
    const int total = Nn * 128;
    const float4* ss4 = (const float4*)ss;
    for (int idx = blockIdx.x * blockDim.x + threadIdx.x; idx < total;
         idx += gridDim.x * blockDim.x) {
        int c = idx & 127;
        ushort4 u = *(const ushort4*)(hhf + (size_t)idx * 4);
        float4 v = make_float4(h2f(u.x), h2f(u.y), h2f(u.z), h2f(u.w));
        float4 a = ss4[c], b = ss4[128 + c];
        v.x = fmaf(v.x, a.x, b.x); v.y = fmaf(v.y, a.y, b.y);
        v.z = fmaf(v.z, a.z, b.z); v.w = fmaf(v.w, a.w, b.w);
        h4[idx] = v;
    }
}

// ---------------- graph mean pool: read f16 hh + fused BN affine (batch sorted)
__global__ void k_pool(const unsigned short* __restrict__ hhf, const float* __restrict__ ss,
                       const int* __restrict__ batch, float* __restrict__ graph) {
    int g = blockIdx.x, t = threadIdx.x;  // 512 blocks, 256 threads
    int lo = 0, hi = Nn;
    while (lo < hi) { int m = (lo + hi) >> 1; if (batch[m] < g) lo = m + 1; else hi = m; }
    int s = lo;
    lo = s; hi = Nn;
    while (lo < hi) { int m = (lo + hi) >> 1; if (batch[m] <= g) lo = m + 1; else hi = m; }
    int e = lo;
    float a0 = ss[t], a1 = ss[t + 256];
    float b0 = ss[512 + t], b1 = ss[512 + t + 256];
    float s0 = 0.f, s1 = 0.f;
    for (int r = s; r < e; ++r) {
        const unsigned short* row = hhf + (size_t)r * Dd;
        s0 += fmaf(h2f(row[t]), a0, b0);
        s1 += fmaf(h2f(row[t + 256]), a1, b1);
    }
    int cnt = e - s; if (cnt < 1) cnt = 1;
    float inv = 1.f / (float)cnt;
    graph[(long)g * Dd + t] = s0 * inv;
    graph[(long)g * Dd + t + 256] = s1 * inv;
}

extern "C" void kernel_launch(void* const* d_in, const int* in_sizes, int n_in,
                              void* d_out, int out_size, void* d_ws, size_t ws_size,
                              hipStream_t stream) {
    (void)in_sizes; (void)n_in; (void)out_size; (void)ws_size;
    const int* x      = (const int*)d_in[0];
    const int* ei     = (const int*)d_in[1];
    const int* ea     = (const int*)d_in[2];
    const int* batch  = (const int*)d_in[3];
    const float* xe1  = (const float*)d_in[4];
    const float* xe2  = (const float*)d_in[5];
    const float* ee1  = (const float*)d_in[6];
    const float* ee2  = (const float*)d_in[7];
    const float* W1   = (const float*)d_in[8];
    const float* b1   = (const float*)d_in[9];
    const float* W2   = (const float*)d_in[10];
    const float* b2   = (const float*)d_in[11];
    const float* gamma = (const float*)d_in[12];
    const float* beta  = (const float*)d_in[13];

    float* graph = (float*)d_out;
    float* h = graph + (size_t)Gg * Dd;  // N*D f32; aliased as hh1 f16 [N][2D]

    // d_ws layout (~143 MB): small/index arrays FIRST, then big buffers.
    char* w = (char*)d_ws;
    int* csr_off = (int*)w;                     w += (Nn + 1) * 4;
    int* cursor = (int*)w;                      w += Nn * 4;
    int* cnt = (int*)w;                         w += Nn * 4;
    int* ckey = (int*)w;                        w += Ee * 4;
    int* csrc = (int*)w;                        w += Ee * 4;
    float* ss = (float*)w;                      w += 4096;
    float* pS = (float*)w;                      w += 2 * 512 * 512 * 4;     // BN partials, 2 MB
    float* pT = (float*)w;                      w += 2 * 64 * 512 * 4;      // BN stage-2, 256 KB
    float* Etab = (float*)w;                    w += (size_t)Ll * 18 * Dd * 4;  // 184 KB
    unsigned short* aggh = (unsigned short*)w;  w += (size_t)Nn * Dd * 2;   // agg f16, 64 MB
    unsigned short* hhf = (unsigned short*)w;   w += (size_t)Nn * Dd * 2;   // hh f16, 64 MB
    unsigned short* w1t = (unsigned short*)w;   w += (size_t)Ll * D2 * Dd * 2;
    unsigned short* w2t = (unsigned short*)w;   w += (size_t)Ll * Dd * D2 * 2;

    // weights -> f16 transposed [N][K]; edge-emb table; atom embedding (f16 h0)
    k_transW<<<2048, 256, 0, stream>>>(W1, w1t, Dd, D2);
    k_transW<<<2048, 256, 0, stream>>>(W2, w2t, D2, Dd);
    k_etab<<<(Ll * 18 * Dd + 255) / 256, 256, 0, stream>>>(ee1, ee2, Etab);
    k_embed<<<2048, 256, 0, stream>>>(x, xe1, xe2, hhf);

    // CSR build (topology constant across layers); sorted -> bit-deterministic
    k_zeroN<<<64, 1024, 0, stream>>>(cnt, Nn);
    k_hist<<<Ee / 256, 256, 0, stream>>>(ei + Ee, cnt);
    k_scan<<<1, 1024, 0, stream>>>(cnt, csr_off, cursor);
    k_place<<<Ee / 256, 256, 0, stream>>>(ei, ei + Ee, ea, cursor, ckey, csrc);
    k_sort<<<Nn / 256, 256, 0, stream>>>(csr_off, ckey, csrc);

    for (int l = 0; l < Ll; ++l) {
        const float* El = Etab + (size_t)l * 18 * Dd;
        if (l == 0)
            k_gather<0><<<Nn / 4, 256, 0, stream>>>(hhf, nullptr, csr_off, ckey, csrc,
                                                    El, aggh);
        else
            k_gather<1><<<Nn / 4, 256, 0, stream>>>(hhf, ss, csr_off, ckey, csrc,
                                                    El, aggh);
        gemm_ov<0><<<(Nn / 256) * (D2 / 128), 256, 0, stream>>>(
            aggh, w1t + (size_t)l * D2 * Dd, b1 + (size_t)l * D2,
            (unsigned short*)h, nullptr, Nn, D2, Dd);
        gemm_ov<1><<<(Nn / 256) * (Dd / 128), 256, 0, stream>>>(
            (const unsigned short*)h, w2t + (size_t)l * Dd * D2, b2 + (size_t)l * Dd,
            hhf, pS, Nn, Dd, D2);
        k_bnA<<<64, 256, 0, stream>>>(pS, pT);
        k_bnB<<<1, 512, 0, stream>>>(pT, gamma + (size_t)l * Dd, beta + (size_t)l * Dd, ss);
    }

    // final-layer BN (no relu) -> h f32, then pool (pool reads f16 hh directly)
    k_norm<<<2048, 256, 0, stream>>>(hhf, ss, (float4*)h);
    k_pool<<<Gg, 256, 0, stream>>>(hhf, ss, batch, graph);
}